// Round 7
// baseline (1411.293 us; speedup 1.0000x reference)
//
#include <hip/hip_runtime.h>
#include <hip/hip_bf16.h>

#define BATCH 512
#define SEQ   500
#define BS    (BATCH*SEQ)     // 256000
#define MEM   64
#define DK    128
#define DV    256
#define FC    128

typedef float f32x4 __attribute__((ext_vector_type(4)));
typedef unsigned short u16x8 __attribute__((ext_vector_type(8)));
typedef __bf16 bf16x8 __attribute__((ext_vector_type(8)));

__device__ __forceinline__ float bf2f(unsigned short u){ return __uint_as_float(((unsigned)u)<<16); }
__device__ __forceinline__ unsigned short f2bfu(float x){
  unsigned u = __float_as_uint(x);
  return (unsigned short)((u + 0x7FFFu + ((u>>16)&1u)) >> 16);  // RNE
}
__device__ __forceinline__ float sigf(float x){ return 1.f/(1.f+__expf(-x)); }
__device__ __forceinline__ float tanh_fast(float x){ return 2.f/(1.f+__expf(-2.f*x)) - 1.f; }

__device__ __forceinline__ float ldF(const void* p, long i, int f32m){
  return f32m ? ((const float*)p)[i] : bf2f(((const unsigned short*)p)[i]);
}
__device__ __forceinline__ int ldI(const int* p, long i, int i64m){
  return i64m ? p[2*i] : p[i];   // little-endian low word of int64
}
__device__ __forceinline__ void st8(unsigned short* dst, const void* src, long i, int f32m){
  if (f32m){
    const float* q = (const float*)src + i;
    f32x4 a = *(const f32x4*)q;
    f32x4 b = *(const f32x4*)(q+4);
    u16x8 o;
    o[0]=f2bfu(a[0]); o[1]=f2bfu(a[1]); o[2]=f2bfu(a[2]); o[3]=f2bfu(a[3]);
    o[4]=f2bfu(b[0]); o[5]=f2bfu(b[1]); o[6]=f2bfu(b[2]); o[7]=f2bfu(b[3]);
    *(u16x8*)dst = o;
  } else {
    *(u16x8*)dst = *(const u16x8*)((const unsigned short*)src + i);
  }
}
__device__ __forceinline__ void stOut(void* p, long i, float x, int f32m){
  if (f32m) ((float*)p)[i] = x;
  else ((unsigned short*)p)[i] = f2bfu(x);
}

// ---------------- K0: dtype detection + accum zero ----------------
__global__ void k_detect(const unsigned short* __restrict__ km, const int* __restrict__ qa,
                         int* __restrict__ flags, float* __restrict__ accum){
  int t = threadIdx.x;            // 64 threads, one wave
  if (t < 2) accum[t] = 0.f;
  unsigned short u = km[2*t];     // even u16 halves of key_memory
  int e = (u >> 7) & 0xFF;
  bool sane = (e==0) || (e>=100 && e<=140);
  unsigned long long sm = __ballot(sane);
  unsigned long long zm = __ballot(qa[2*t+1] == 0);
  if (t == 0){
    flags[0] = (__popcll(sm) < 48) ? 1 : 0;               // 1 = f32 float buffers
    flags[1] = (zm == 0xFFFFFFFFFFFFFFFFull) ? 1 : 0;     // 1 = int64 index buffers
  }
}

// ---------------- K1: cw = softmax(q_e @ key^T) ----------------
__global__ __launch_bounds__(256, 2) void k_cw(const int* __restrict__ qd,
    const void* __restrict__ qW, const void* __restrict__ keym,
    float* __restrict__ cw, const int* __restrict__ flags){
  const int f32m = flags[0], i64m = flags[1];
  __shared__ float keyT[DK][MEM];
  int t = threadIdx.x;
  for (int i=t;i<MEM*DK;i+=256){ int m=i&63, k=i>>6; keyT[k][m] = ldF(keym, (long)m*DK+k, f32m); }
  __syncthreads();
  long row = (long)blockIdx.x*256 + t;
  int qid = ldI(qd, row, i64m);
  long qb = (long)qid*DK;
  f32x4 A[16];
  #pragma unroll
  for (int g=0;g<16;g++) A[g] = (f32x4){0.f,0.f,0.f,0.f};
  for (int kk=0;kk<DK;kk+=8){
    float qv[8];
    if (f32m){
      const float* qp = (const float*)qW + qb + kk;
      f32x4 a=*(const f32x4*)qp, b=*(const f32x4*)(qp+4);
      qv[0]=a[0];qv[1]=a[1];qv[2]=a[2];qv[3]=a[3];qv[4]=b[0];qv[5]=b[1];qv[6]=b[2];qv[7]=b[3];
    } else {
      u16x8 u = *(const u16x8*)((const unsigned short*)qW + qb + kk);
      #pragma unroll
      for (int j=0;j<8;j++) qv[j]=bf2f(u[j]);
    }
    #pragma unroll
    for (int j=0;j<8;j++){
      float q = qv[j];
      #pragma unroll
      for (int g=0;g<16;g++){
        f32x4 kv = *(const f32x4*)&keyT[kk+j][g*4];
        f32x4 a = A[g];
        a[0]=fmaf(q,kv[0],a[0]); a[1]=fmaf(q,kv[1],a[1]);
        a[2]=fmaf(q,kv[2],a[2]); a[3]=fmaf(q,kv[3],a[3]);
        A[g]=a;
      }
    }
  }
  float mx = -1e30f;
  #pragma unroll
  for (int g=0;g<16;g++){
    f32x4 a = A[g];
    mx = fmaxf(mx, fmaxf(fmaxf(a[0],a[1]), fmaxf(a[2],a[3])));
  }
  float sum = 0.f;
  #pragma unroll
  for (int g=0;g<16;g++){
    f32x4 a = A[g];
    a[0]=__expf(a[0]-mx); a[1]=__expf(a[1]-mx); a[2]=__expf(a[2]-mx); a[3]=__expf(a[3]-mx);
    sum += (a[0]+a[1])+(a[2]+a[3]);
    A[g]=a;
  }
  float inv = 1.f/sum;
  float* outp = cw + row*MEM;
  #pragma unroll
  for (int g=0;g<16;g++){
    f32x4 a = A[g];
    f32x4 v = { a[0]*inv, a[1]*inv, a[2]*inv, a[3]*inv };
    *(f32x4*)(outp + g*4) = v;
  }
}

// ---------------- K2 (per-chunk): [erase|add] -> interleaved (er[d],ad[d]) u16 pairs ----------------
__global__ __launch_bounds__(256, 2) void k_ea(const int* __restrict__ qad, long row0,
    const void* __restrict__ qaW, const void* __restrict__ eW, const void* __restrict__ ebias,
    const void* __restrict__ aW, const void* __restrict__ abias,
    unsigned short* __restrict__ ea, const int* __restrict__ flags){
  const int f32m = flags[0], i64m = flags[1];
  __shared__ unsigned short As[128][40];
  __shared__ unsigned short Bs[128][40];
  __shared__ int rid[128];
  int t = threadIdx.x;
  int bm = blockIdx.x, bn = blockIdx.y;
  if (t<128) rid[t] = ldI(qad, row0 + (long)bm*128+t, i64m);
  int lane = t & 63, wid = t >> 6;
  int wr = wid >> 1, wc = wid & 1;
  f32x4 acc[4][4] = {};
  for (int k0=0;k0<DV;k0+=32){
    __syncthreads();
    #pragma unroll
    for (int j=0;j<2;j++){
      int c = t*2+j, r = c>>2, ko = (c&3)*8;
      st8(&As[r][ko], qaW, (long)rid[r]*DV + k0 + ko, f32m);
      int gn = bn*128 + r;
      if (gn < DV) st8(&Bs[r][ko], eW, (long)gn*DV + k0 + ko, f32m);
      else         st8(&Bs[r][ko], aW, (long)(gn-DV)*DV + k0 + ko, f32m);
    }
    __syncthreads();
    bf16x8 af[4], bfr[4];
    #pragma unroll
    for (int i=0;i<4;i++){
      af[i]  = __builtin_bit_cast(bf16x8, *(const u16x8*)&As[wr*64+i*16+(lane&15)][(lane>>4)*8]);
      bfr[i] = __builtin_bit_cast(bf16x8, *(const u16x8*)&Bs[wc*64+i*16+(lane&15)][(lane>>4)*8]);
    }
    #pragma unroll
    for (int i=0;i<4;i++)
      #pragma unroll
      for (int n=0;n<4;n++)
        acc[i][n] = __builtin_amdgcn_mfma_f32_16x16x32_bf16(af[i], bfr[n], acc[i][n],0,0,0);
  }
  #pragma unroll
  for (int i=0;i<4;i++)
    #pragma unroll
    for (int n=0;n<4;n++){
      int col = bn*128 + wc*64 + n*16 + (lane&15);
      float bias = (col<DV) ? ldF(ebias,col,f32m) : ldF(abias,col-DV,f32m);
      int dcol = (col<DV) ? 2*col : 2*(col-DV)+1;   // interleaved pair layout
      #pragma unroll
      for (int rix=0;rix<4;rix++){
        long rowg = (long)bm*128 + wr*64 + i*16 + (lane>>4)*4 + rix;
        float v = acc[i][n][rix] + bias;
        float o = (col<DV) ? sigf(v) : tanh_fast(v);
        ea[rowg*(2*DV) + dcol] = f2bfu(o);
      }
    }
}

// ---------------- K3 (per-chunk): scan, m split 8-ways, d split 2 blocks ----------------
// thread (d, q=tid&7) owns m in [8q, 8q+8)
// incremental pointers + immediate offsets; er/ad come packed in one u32
#define SCAN_STEP(W0, W1, U, RDOFF) { \
  float er = bf2f((unsigned short)((U) & 0xFFFFu)); \
  float ad = bf2f((unsigned short)((U) >> 16)); \
  float r0,r1,r2,r3; \
  { f32x4 w = W0; f32x4 m = M0; \
    r0 = w[0]*m[0]; r1 = w[1]*m[1]; r2 = w[2]*m[2]; r3 = w[3]*m[3]; \
    f32x4 tt; \
    tt[0] = fmaf(m[0], er, -ad); tt[1] = fmaf(m[1], er, -ad); \
    tt[2] = fmaf(m[2], er, -ad); tt[3] = fmaf(m[3], er, -ad); \
    m[0] = fmaf(-w[0], tt[0], m[0]); m[1] = fmaf(-w[1], tt[1], m[1]); \
    m[2] = fmaf(-w[2], tt[2], m[2]); m[3] = fmaf(-w[3], tt[3], m[3]); \
    M0 = m; } \
  { f32x4 w = W1; f32x4 m = M1; \
    r0 = fmaf(w[0], m[0], r0); r1 = fmaf(w[1], m[1], r1); \
    r2 = fmaf(w[2], m[2], r2); r3 = fmaf(w[3], m[3], r3); \
    f32x4 tt; \
    tt[0] = fmaf(m[0], er, -ad); tt[1] = fmaf(m[1], er, -ad); \
    tt[2] = fmaf(m[2], er, -ad); tt[3] = fmaf(m[3], er, -ad); \
    m[0] = fmaf(-w[0], tt[0], m[0]); m[1] = fmaf(-w[1], tt[1], m[1]); \
    m[2] = fmaf(-w[2], tt[2], m[2]); m[3] = fmaf(-w[3], tt[3], m[3]); \
    M1 = m; } \
  float r = (r0+r1)+(r2+r3); \
  r += __shfl_xor(r, 1); \
  r += __shfl_xor(r, 2); \
  r += __shfl_xor(r, 4); \
  if (q == 0) rdp[RDOFF] = f2bfu(r); \
}

__global__ __launch_bounds__(1024, 8) void k_scan(const float* __restrict__ cw,
    const unsigned short* __restrict__ ea, const void* __restrict__ initm,
    unsigned short* __restrict__ rdout, const int* __restrict__ flags){
  const int f32m = flags[0];
  int b = blockIdx.x;
  int t = threadIdx.x;
  int q = t & 7;
  int d = (int)blockIdx.y*128 + (t >> 3);
  int m0 = q * 8;
  f32x4 M0, M1;
  #pragma unroll
  for (int j=0;j<4;j++) M0[j] = ldF(initm, (long)(m0+j)*DV + d, f32m);
  #pragma unroll
  for (int j=0;j<4;j++) M1[j] = ldF(initm, (long)(m0+4+j)*DV + d, f32m);
  const float* wp = cw + (long)b*SEQ*MEM + m0;
  const unsigned int* ep = (const unsigned int*)(ea + (long)b*SEQ*(2*DV)) + d;  // 256 u32/row
  unsigned short* rdp = rdout + (long)b*SEQ*DV + d;
  f32x4 WA0 = *(const f32x4*)(wp);
  f32x4 WA1 = *(const f32x4*)(wp+4);
  unsigned int uA = ep[0];
  for (int s=0; s<SEQ; s+=2){
    // step s+1 data (immediate offsets off running pointers)
    f32x4 WB0 = *(const f32x4*)(wp+64);
    f32x4 WB1 = *(const f32x4*)(wp+68);
    unsigned int uB = ep[256];
    SCAN_STEP(WA0, WA1, uA, 0);
    // prefetch step s+2 (tail over-read stays inside workspace; values unused)
    WA0 = *(const f32x4*)(wp+128);
    WA1 = *(const f32x4*)(wp+132);
    uA = ep[512];
    SCAN_STEP(WB0, WB1, uB, DV);
    wp += 2*MEM; ep += 512; rdp += 2*DV;
  }
}

// ---------------- K4 (per-chunk): h = tanh([reads|q_e] @ rW^T + rb); logit; BCE ----------------
__global__ __launch_bounds__(256, 2) void k_pred(const int* __restrict__ qd, long row0,
    const void* __restrict__ qW, const unsigned short* __restrict__ rds,
    const void* __restrict__ rW, const void* __restrict__ rb,
    const void* __restrict__ pW, const void* __restrict__ pb,
    const void* __restrict__ target,
    void* __restrict__ out, float* __restrict__ accum,
    const int* __restrict__ flags){
  const int f32m = flags[0], i64m = flags[1];
  __shared__ unsigned short As[128][40];
  __shared__ unsigned short Bs[128][40];
  __shared__ unsigned short hs[128][136];
  __shared__ int rid[128];
  int t = threadIdx.x;
  int bm = blockIdx.x;
  if (t<128) rid[t] = ldI(qd, row0 + (long)bm*128+t, i64m);
  int lane=t&63, wid=t>>6, wr=wid>>1, wc=wid&1;
  f32x4 acc[4][4] = {};
  for (int k0=0;k0<(DV+DK);k0+=32){
    __syncthreads();
    #pragma unroll
    for (int j=0;j<2;j++){
      int c=t*2+j, r=c>>2, ko=(c&3)*8;
      if (k0 < DV) st8(&As[r][ko], rds, ((long)bm*128+r)*DV + k0+ko, 0);
      else         st8(&As[r][ko], qW, (long)rid[r]*DK + (k0-DV)+ko, f32m);
      st8(&Bs[r][ko], rW, (long)r*(DV+DK) + k0+ko, f32m);
    }
    __syncthreads();
    bf16x8 af[4], bfr[4];
    #pragma unroll
    for (int i=0;i<4;i++){
      af[i]  = __builtin_bit_cast(bf16x8, *(const u16x8*)&As[wr*64+i*16+(lane&15)][(lane>>4)*8]);
      bfr[i] = __builtin_bit_cast(bf16x8, *(const u16x8*)&Bs[wc*64+i*16+(lane&15)][(lane>>4)*8]);
    }
    #pragma unroll
    for (int i=0;i<4;i++)
      #pragma unroll
      for (int n=0;n<4;n++)
        acc[i][n] = __builtin_amdgcn_mfma_f32_16x16x32_bf16(af[i], bfr[n], acc[i][n],0,0,0);
  }
  #pragma unroll
  for (int i=0;i<4;i++)
    #pragma unroll
    for (int n=0;n<4;n++){
      int col = wc*64 + n*16 + (lane&15);
      float bias = ldF(rb, col, f32m);
      #pragma unroll
      for (int rix=0;rix<4;rix++){
        int rowl = wr*64 + i*16 + (lane>>4)*4 + rix;
        hs[rowl][col] = f2bfu(tanh_fast(acc[i][n][rix] + bias));
      }
    }
  __syncthreads();
  float bces = 0.f, cnts = 0.f;
  if (t < 128){
    float lg = ldF(pb, 0, f32m);
    #pragma unroll
    for (int cc=0;cc<FC;cc++) lg = fmaf(bf2f(hs[t][cc]), ldF(pW, cc, f32m), lg);
    long rowg = row0 + (long)bm*128 + t;
    float tg = ldF(target, rowg, f32m);
    bool mask = tg >= 0.f;
    float e = __expf(-fabsf(lg));
    float bce = fmaxf(lg, 0.f) - lg*tg + __logf(1.f + e);
    bces = mask ? bce : 0.f;
    cnts = mask ? 1.f : 0.f;
    stOut(out, 1 + rowg, mask ? sigf(lg) : 0.f, f32m);
    stOut(out, 1 + BS + rowg, mask ? tg : 0.f, f32m);
  }
  #pragma unroll
  for (int off=32; off>0; off>>=1){ bces += __shfl_down(bces, off); cnts += __shfl_down(cnts, off); }
  if ((t & 63) == 0 && t < 128){
    atomicAdd(&accum[0], bces);
    atomicAdd(&accum[1], cnts);
  }
}

__global__ void k_loss(const float* __restrict__ accum, void* __restrict__ out,
                       const int* __restrict__ flags){
  if (threadIdx.x == 0){
    float denom = fmaxf(accum[1], 1.f);
    stOut(out, 0, accum[0]/denom, flags[0]);
  }
}

extern "C" void kernel_launch(void* const* d_in, const int* in_sizes, int n_in,
                              void* d_out, int out_size, void* d_ws, size_t ws_size,
                              hipStream_t stream) {
  const int* q_data  = (const int*)d_in[0];
  const int* qa_data = (const int*)d_in[1];
  const void* target = d_in[2];
  const void* qW   = d_in[3];
  const void* qaW  = d_in[4];
  const void* keym = d_in[5];
  const void* initm= d_in[6];
  const void* eW   = d_in[7];
  const void* eb   = d_in[8];
  const void* aW   = d_in[9];
  const void* ab   = d_in[10];
  const void* rW   = d_in[11];
  const void* rb   = d_in[12];
  const void* pW   = d_in[13];
  const void* pb   = d_in[14];

  char* ws = (char*)d_ws;
  const size_t CW_OFF = 256;
  const size_t CW_BYTES = (size_t)BS*MEM*4;              // 65,536,000
  const size_t EA_OFF = CW_OFF + CW_BYTES;
  float* accum = (float*)ws;
  int* flags = (int*)(ws + 64);
  float* cw = (float*)(ws + CW_OFF);

  const long per_batch = (long)SEQ*(2*DV)*2 + (long)SEQ*DV*2;  // 768000 B per batch
  long rem = (long)ws_size - (long)EA_OFF;
  int bchunk = 512;
  while (bchunk > 32 && per_batch*bchunk > rem) bchunk >>= 1;  // 512,256,128,64,32

  const size_t EA_BYTES = (size_t)bchunk*SEQ*(2*DV)*2;
  unsigned short* ea = (unsigned short*)(ws + EA_OFF);
  unsigned short* rd = (unsigned short*)(ws + EA_OFF + EA_BYTES);

  k_detect<<<1, 64, 0, stream>>>((const unsigned short*)keym, qa_data, flags, accum);
  k_cw  <<<BS/256, 256, 0, stream>>>(q_data, qW, keym, cw, flags);

  int nchunk = BATCH / bchunk;
  for (int c = 0; c < nchunk; c++){
    long b0 = (long)c * bchunk;
    int rows = bchunk * SEQ;
    k_ea  <<<dim3(rows/128, 4), 256, 0, stream>>>(qa_data, b0*SEQ, qaW, eW, eb, aW, ab, ea, flags);
    k_scan<<<dim3(bchunk, 2), 1024, 0, stream>>>(cw + b0*SEQ*MEM, ea, initm, rd, flags);
    k_pred<<<rows/128, 256, 0, stream>>>(q_data, b0*SEQ, qW, rd, rW, rb, pW, pb,
                                         target, d_out, accum, flags);
  }
  k_loss<<<1, 64, 0, stream>>>(accum, d_out, flags);
}

// Round 8
// 1353.359 us; speedup vs baseline: 1.0428x; 1.0428x over previous
//
#include <hip/hip_runtime.h>
#include <hip/hip_bf16.h>

#define BATCH 512
#define SEQ   500
#define BS    (BATCH*SEQ)     // 256000
#define MEM   64
#define DK    128
#define DV    256
#define FC    128
#define PD    4               // scan prefetch depth (steps)

typedef float f32x4 __attribute__((ext_vector_type(4)));
typedef unsigned short u16x8 __attribute__((ext_vector_type(8)));
typedef __bf16 bf16x8 __attribute__((ext_vector_type(8)));

__device__ __forceinline__ float bf2f(unsigned short u){ return __uint_as_float(((unsigned)u)<<16); }
__device__ __forceinline__ unsigned short f2bfu(float x){
  unsigned u = __float_as_uint(x);
  return (unsigned short)((u + 0x7FFFu + ((u>>16)&1u)) >> 16);  // RNE
}
__device__ __forceinline__ float sigf(float x){ return 1.f/(1.f+__expf(-x)); }
__device__ __forceinline__ float tanh_fast(float x){ return 2.f/(1.f+__expf(-2.f*x)) - 1.f; }

__device__ __forceinline__ float ldF(const void* p, long i, int f32m){
  return f32m ? ((const float*)p)[i] : bf2f(((const unsigned short*)p)[i]);
}
__device__ __forceinline__ int ldI(const int* p, long i, int i64m){
  return i64m ? p[2*i] : p[i];   // little-endian low word of int64
}
__device__ __forceinline__ void st8(unsigned short* dst, const void* src, long i, int f32m){
  if (f32m){
    const float* q = (const float*)src + i;
    f32x4 a = *(const f32x4*)q;
    f32x4 b = *(const f32x4*)(q+4);
    u16x8 o;
    o[0]=f2bfu(a[0]); o[1]=f2bfu(a[1]); o[2]=f2bfu(a[2]); o[3]=f2bfu(a[3]);
    o[4]=f2bfu(b[0]); o[5]=f2bfu(b[1]); o[6]=f2bfu(b[2]); o[7]=f2bfu(b[3]);
    *(u16x8*)dst = o;
  } else {
    *(u16x8*)dst = *(const u16x8*)((const unsigned short*)src + i);
  }
}
__device__ __forceinline__ void stOut(void* p, long i, float x, int f32m){
  if (f32m) ((float*)p)[i] = x;
  else ((unsigned short*)p)[i] = f2bfu(x);
}

// ---------------- K0: dtype detection + accum zero ----------------
__global__ void k_detect(const unsigned short* __restrict__ km, const int* __restrict__ qa,
                         int* __restrict__ flags, float* __restrict__ accum){
  int t = threadIdx.x;            // 64 threads, one wave
  if (t < 2) accum[t] = 0.f;
  unsigned short u = km[2*t];     // even u16 halves of key_memory
  int e = (u >> 7) & 0xFF;
  bool sane = (e==0) || (e>=100 && e<=140);
  unsigned long long sm = __ballot(sane);
  unsigned long long zm = __ballot(qa[2*t+1] == 0);
  if (t == 0){
    flags[0] = (__popcll(sm) < 48) ? 1 : 0;               // 1 = f32 float buffers
    flags[1] = (zm == 0xFFFFFFFFFFFFFFFFull) ? 1 : 0;     // 1 = int64 index buffers
  }
}

// ---------------- K1: cw = softmax(q_e @ key^T) ----------------
__global__ __launch_bounds__(256, 2) void k_cw(const int* __restrict__ qd,
    const void* __restrict__ qW, const void* __restrict__ keym,
    float* __restrict__ cw, const int* __restrict__ flags){
  const int f32m = flags[0], i64m = flags[1];
  __shared__ float keyT[DK][MEM];
  int t = threadIdx.x;
  for (int i=t;i<MEM*DK;i+=256){ int m=i&63, k=i>>6; keyT[k][m] = ldF(keym, (long)m*DK+k, f32m); }
  __syncthreads();
  long row = (long)blockIdx.x*256 + t;
  int qid = ldI(qd, row, i64m);
  long qb = (long)qid*DK;
  f32x4 A[16];
  #pragma unroll
  for (int g=0;g<16;g++) A[g] = (f32x4){0.f,0.f,0.f,0.f};
  for (int kk=0;kk<DK;kk+=8){
    float qv[8];
    if (f32m){
      const float* qp = (const float*)qW + qb + kk;
      f32x4 a=*(const f32x4*)qp, b=*(const f32x4*)(qp+4);
      qv[0]=a[0];qv[1]=a[1];qv[2]=a[2];qv[3]=a[3];qv[4]=b[0];qv[5]=b[1];qv[6]=b[2];qv[7]=b[3];
    } else {
      u16x8 u = *(const u16x8*)((const unsigned short*)qW + qb + kk);
      #pragma unroll
      for (int j=0;j<8;j++) qv[j]=bf2f(u[j]);
    }
    #pragma unroll
    for (int j=0;j<8;j++){
      float q = qv[j];
      #pragma unroll
      for (int g=0;g<16;g++){
        f32x4 kv = *(const f32x4*)&keyT[kk+j][g*4];
        f32x4 a = A[g];
        a[0]=fmaf(q,kv[0],a[0]); a[1]=fmaf(q,kv[1],a[1]);
        a[2]=fmaf(q,kv[2],a[2]); a[3]=fmaf(q,kv[3],a[3]);
        A[g]=a;
      }
    }
  }
  float mx = -1e30f;
  #pragma unroll
  for (int g=0;g<16;g++){
    f32x4 a = A[g];
    mx = fmaxf(mx, fmaxf(fmaxf(a[0],a[1]), fmaxf(a[2],a[3])));
  }
  float sum = 0.f;
  #pragma unroll
  for (int g=0;g<16;g++){
    f32x4 a = A[g];
    a[0]=__expf(a[0]-mx); a[1]=__expf(a[1]-mx); a[2]=__expf(a[2]-mx); a[3]=__expf(a[3]-mx);
    sum += (a[0]+a[1])+(a[2]+a[3]);
    A[g]=a;
  }
  float inv = 1.f/sum;
  float* outp = cw + row*MEM;
  #pragma unroll
  for (int g=0;g<16;g++){
    f32x4 a = A[g];
    f32x4 v = { a[0]*inv, a[1]*inv, a[2]*inv, a[3]*inv };
    *(f32x4*)(outp + g*4) = v;
  }
}

// ---------------- K2 (per-chunk): [erase|add] -> interleaved (er[d],ad[d]) u16 pairs ----------------
__global__ __launch_bounds__(256, 2) void k_ea(const int* __restrict__ qad, long row0,
    const void* __restrict__ qaW, const void* __restrict__ eW, const void* __restrict__ ebias,
    const void* __restrict__ aW, const void* __restrict__ abias,
    unsigned short* __restrict__ ea, const int* __restrict__ flags){
  const int f32m = flags[0], i64m = flags[1];
  __shared__ unsigned short As[128][40];
  __shared__ unsigned short Bs[128][40];
  __shared__ int rid[128];
  int t = threadIdx.x;
  int bm = blockIdx.x, bn = blockIdx.y;
  if (t<128) rid[t] = ldI(qad, row0 + (long)bm*128+t, i64m);
  int lane = t & 63, wid = t >> 6;
  int wr = wid >> 1, wc = wid & 1;
  f32x4 acc[4][4] = {};
  for (int k0=0;k0<DV;k0+=32){
    __syncthreads();
    #pragma unroll
    for (int j=0;j<2;j++){
      int c = t*2+j, r = c>>2, ko = (c&3)*8;
      st8(&As[r][ko], qaW, (long)rid[r]*DV + k0 + ko, f32m);
      int gn = bn*128 + r;
      if (gn < DV) st8(&Bs[r][ko], eW, (long)gn*DV + k0 + ko, f32m);
      else         st8(&Bs[r][ko], aW, (long)(gn-DV)*DV + k0 + ko, f32m);
    }
    __syncthreads();
    bf16x8 af[4], bfr[4];
    #pragma unroll
    for (int i=0;i<4;i++){
      af[i]  = __builtin_bit_cast(bf16x8, *(const u16x8*)&As[wr*64+i*16+(lane&15)][(lane>>4)*8]);
      bfr[i] = __builtin_bit_cast(bf16x8, *(const u16x8*)&Bs[wc*64+i*16+(lane&15)][(lane>>4)*8]);
    }
    #pragma unroll
    for (int i=0;i<4;i++)
      #pragma unroll
      for (int n=0;n<4;n++)
        acc[i][n] = __builtin_amdgcn_mfma_f32_16x16x32_bf16(af[i], bfr[n], acc[i][n],0,0,0);
  }
  #pragma unroll
  for (int i=0;i<4;i++)
    #pragma unroll
    for (int n=0;n<4;n++){
      int col = bn*128 + wc*64 + n*16 + (lane&15);
      float bias = (col<DV) ? ldF(ebias,col,f32m) : ldF(abias,col-DV,f32m);
      int dcol = (col<DV) ? 2*col : 2*(col-DV)+1;   // interleaved pair layout
      #pragma unroll
      for (int rix=0;rix<4;rix++){
        long rowg = (long)bm*128 + wr*64 + i*16 + (lane>>4)*4 + rix;
        float v = acc[i][n][rix] + bias;
        float o = (col<DV) ? sigf(v) : tanh_fast(v);
        ea[rowg*(2*DV) + dcol] = f2bfu(o);
      }
    }
}

// ---------------- K3 (per-chunk): scan, m split 8-ways, 4-deep prefetch pipeline ----------------
// thread (d, q=tid&7) owns m in [8q, 8q+8)
#define SCAN_STEP(W0v, W1v, U, RDOFF) { \
  float er = bf2f((unsigned short)((U) & 0xFFFFu)); \
  float ad = bf2f((unsigned short)((U) >> 16)); \
  float r0,r1,r2,r3; \
  { f32x4 w = W0v; f32x4 m = M0; \
    r0 = w[0]*m[0]; r1 = w[1]*m[1]; r2 = w[2]*m[2]; r3 = w[3]*m[3]; \
    f32x4 tt; \
    tt[0] = fmaf(m[0], er, -ad); tt[1] = fmaf(m[1], er, -ad); \
    tt[2] = fmaf(m[2], er, -ad); tt[3] = fmaf(m[3], er, -ad); \
    m[0] = fmaf(-w[0], tt[0], m[0]); m[1] = fmaf(-w[1], tt[1], m[1]); \
    m[2] = fmaf(-w[2], tt[2], m[2]); m[3] = fmaf(-w[3], tt[3], m[3]); \
    M0 = m; } \
  { f32x4 w = W1v; f32x4 m = M1; \
    r0 = fmaf(w[0], m[0], r0); r1 = fmaf(w[1], m[1], r1); \
    r2 = fmaf(w[2], m[2], r2); r3 = fmaf(w[3], m[3], r3); \
    f32x4 tt; \
    tt[0] = fmaf(m[0], er, -ad); tt[1] = fmaf(m[1], er, -ad); \
    tt[2] = fmaf(m[2], er, -ad); tt[3] = fmaf(m[3], er, -ad); \
    m[0] = fmaf(-w[0], tt[0], m[0]); m[1] = fmaf(-w[1], tt[1], m[1]); \
    m[2] = fmaf(-w[2], tt[2], m[2]); m[3] = fmaf(-w[3], tt[3], m[3]); \
    M1 = m; } \
  float r = (r0+r1)+(r2+r3); \
  r += __shfl_xor(r, 1); \
  r += __shfl_xor(r, 2); \
  r += __shfl_xor(r, 4); \
  if (q == 0) rdp[RDOFF] = f2bfu(r); \
}

__global__ __launch_bounds__(1024, 8) void k_scan(const float* __restrict__ cw,
    const unsigned short* __restrict__ ea, const void* __restrict__ initm,
    unsigned short* __restrict__ rdout, const int* __restrict__ flags){
  const int f32m = flags[0];
  int b = blockIdx.x;
  int t = threadIdx.x;
  int q = t & 7;
  int d = (int)blockIdx.y*128 + (t >> 3);
  int m0 = q * 8;
  f32x4 M0, M1;
  #pragma unroll
  for (int j=0;j<4;j++) M0[j] = ldF(initm, (long)(m0+j)*DV + d, f32m);
  #pragma unroll
  for (int j=0;j<4;j++) M1[j] = ldF(initm, (long)(m0+4+j)*DV + d, f32m);
  const float* wp = cw + (long)b*SEQ*MEM + m0;
  const unsigned int* ep = (const unsigned int*)(ea + (long)b*SEQ*(2*DV)) + d;  // 256 u32/row
  unsigned short* rdp = rdout + (long)b*SEQ*DV + d;

  f32x4 W0[PD], W1[PD];
  unsigned int U[PD];
  #pragma unroll
  for (int i=0;i<PD;i++){
    W0[i] = *(const f32x4*)(wp + i*MEM);
    W1[i] = *(const f32x4*)(wp + i*MEM + 4);
    U[i]  = ep[i*256];
  }
  // main: steps 0..SEQ-PD-1 with PD-deep prefetch (SEQ%PD==0 so bound is exact)
  for (int s=0; s<SEQ-PD; s+=PD){
    #pragma unroll
    for (int i=0;i<PD;i++){
      SCAN_STEP(W0[i], W1[i], U[i], i*DV);
      // prefetch step s+PD+i (over-read past batch end stays inside ws; unused)
      W0[i] = *(const f32x4*)(wp + (PD+i)*MEM);
      W1[i] = *(const f32x4*)(wp + (PD+i)*MEM + 4);
      U[i]  = ep[(PD+i)*256];
    }
    wp += PD*MEM; ep += PD*256; rdp += PD*DV;
  }
  // tail: last PD steps, no prefetch
  #pragma unroll
  for (int i=0;i<PD;i++){
    SCAN_STEP(W0[i], W1[i], U[i], i*DV);
  }
}

// ---------------- K4 (per-chunk): h = tanh([reads|q_e] @ rW^T + rb); logit; BCE ----------------
__global__ __launch_bounds__(256, 2) void k_pred(const int* __restrict__ qd, long row0,
    const void* __restrict__ qW, const unsigned short* __restrict__ rds,
    const void* __restrict__ rW, const void* __restrict__ rb,
    const void* __restrict__ pW, const void* __restrict__ pb,
    const void* __restrict__ target,
    void* __restrict__ out, float* __restrict__ accum,
    const int* __restrict__ flags){
  const int f32m = flags[0], i64m = flags[1];
  __shared__ unsigned short As[128][40];
  __shared__ unsigned short Bs[128][40];
  __shared__ unsigned short hs[128][136];
  __shared__ int rid[128];
  int t = threadIdx.x;
  int bm = blockIdx.x;
  if (t<128) rid[t] = ldI(qd, row0 + (long)bm*128+t, i64m);
  int lane=t&63, wid=t>>6, wr=wid>>1, wc=wid&1;
  f32x4 acc[4][4] = {};
  for (int k0=0;k0<(DV+DK);k0+=32){
    __syncthreads();
    #pragma unroll
    for (int j=0;j<2;j++){
      int c=t*2+j, r=c>>2, ko=(c&3)*8;
      if (k0 < DV) st8(&As[r][ko], rds, ((long)bm*128+r)*DV + k0+ko, 0);
      else         st8(&As[r][ko], qW, (long)rid[r]*DK + (k0-DV)+ko, f32m);
      st8(&Bs[r][ko], rW, (long)r*(DV+DK) + k0+ko, f32m);
    }
    __syncthreads();
    bf16x8 af[4], bfr[4];
    #pragma unroll
    for (int i=0;i<4;i++){
      af[i]  = __builtin_bit_cast(bf16x8, *(const u16x8*)&As[wr*64+i*16+(lane&15)][(lane>>4)*8]);
      bfr[i] = __builtin_bit_cast(bf16x8, *(const u16x8*)&Bs[wc*64+i*16+(lane&15)][(lane>>4)*8]);
    }
    #pragma unroll
    for (int i=0;i<4;i++)
      #pragma unroll
      for (int n=0;n<4;n++)
        acc[i][n] = __builtin_amdgcn_mfma_f32_16x16x32_bf16(af[i], bfr[n], acc[i][n],0,0,0);
  }
  #pragma unroll
  for (int i=0;i<4;i++)
    #pragma unroll
    for (int n=0;n<4;n++){
      int col = wc*64 + n*16 + (lane&15);
      float bias = ldF(rb, col, f32m);
      #pragma unroll
      for (int rix=0;rix<4;rix++){
        int rowl = wr*64 + i*16 + (lane>>4)*4 + rix;
        hs[rowl][col] = f2bfu(tanh_fast(acc[i][n][rix] + bias));
      }
    }
  __syncthreads();
  float bces = 0.f, cnts = 0.f;
  if (t < 128){
    float lg = ldF(pb, 0, f32m);
    #pragma unroll
    for (int cc=0;cc<FC;cc++) lg = fmaf(bf2f(hs[t][cc]), ldF(pW, cc, f32m), lg);
    long rowg = row0 + (long)bm*128 + t;
    float tg = ldF(target, rowg, f32m);
    bool mask = tg >= 0.f;
    float e = __expf(-fabsf(lg));
    float bce = fmaxf(lg, 0.f) - lg*tg + __logf(1.f + e);
    bces = mask ? bce : 0.f;
    cnts = mask ? 1.f : 0.f;
    stOut(out, 1 + rowg, mask ? sigf(lg) : 0.f, f32m);
    stOut(out, 1 + BS + rowg, mask ? tg : 0.f, f32m);
  }
  #pragma unroll
  for (int off=32; off>0; off>>=1){ bces += __shfl_down(bces, off); cnts += __shfl_down(cnts, off); }
  if ((t & 63) == 0 && t < 128){
    atomicAdd(&accum[0], bces);
    atomicAdd(&accum[1], cnts);
  }
}

__global__ void k_loss(const float* __restrict__ accum, void* __restrict__ out,
                       const int* __restrict__ flags){
  if (threadIdx.x == 0){
    float denom = fmaxf(accum[1], 1.f);
    stOut(out, 0, accum[0]/denom, flags[0]);
  }
}

extern "C" void kernel_launch(void* const* d_in, const int* in_sizes, int n_in,
                              void* d_out, int out_size, void* d_ws, size_t ws_size,
                              hipStream_t stream) {
  const int* q_data  = (const int*)d_in[0];
  const int* qa_data = (const int*)d_in[1];
  const void* target = d_in[2];
  const void* qW   = d_in[3];
  const void* qaW  = d_in[4];
  const void* keym = d_in[5];
  const void* initm= d_in[6];
  const void* eW   = d_in[7];
  const void* eb   = d_in[8];
  const void* aW   = d_in[9];
  const void* ab   = d_in[10];
  const void* rW   = d_in[11];
  const void* rb   = d_in[12];
  const void* pW   = d_in[13];
  const void* pb   = d_in[14];

  char* ws = (char*)d_ws;
  const size_t CW_OFF = 256;
  const size_t CW_BYTES = (size_t)BS*MEM*4;              // 65,536,000
  const size_t EA_OFF = CW_OFF + CW_BYTES;
  float* accum = (float*)ws;
  int* flags = (int*)(ws + 64);
  float* cw = (float*)(ws + CW_OFF);

  const long per_batch = (long)SEQ*(2*DV)*2 + (long)SEQ*DV*2;  // 768000 B per batch
  long rem = (long)ws_size - (long)EA_OFF;
  int bchunk = 512;
  while (bchunk > 32 && per_batch*bchunk > rem) bchunk >>= 1;  // 512,256,128,64,32

  const size_t EA_BYTES = (size_t)bchunk*SEQ*(2*DV)*2;
  unsigned short* ea = (unsigned short*)(ws + EA_OFF);
  unsigned short* rd = (unsigned short*)(ws + EA_OFF + EA_BYTES);

  k_detect<<<1, 64, 0, stream>>>((const unsigned short*)keym, qa_data, flags, accum);
  k_cw  <<<BS/256, 256, 0, stream>>>(q_data, qW, keym, cw, flags);

  int nchunk = BATCH / bchunk;
  for (int c = 0; c < nchunk; c++){
    long b0 = (long)c * bchunk;
    int rows = bchunk * SEQ;
    k_ea  <<<dim3(rows/128, 4), 256, 0, stream>>>(qa_data, b0*SEQ, qaW, eW, eb, aW, ab, ea, flags);
    k_scan<<<dim3(bchunk, 2), 1024, 0, stream>>>(cw + b0*SEQ*MEM, ea, initm, rd, flags);
    k_pred<<<rows/128, 256, 0, stream>>>(q_data, b0*SEQ, qW, rd, rW, rb, pW, pb,
                                         target, d_out, accum, flags);
  }
  k_loss<<<1, 64, 0, stream>>>(accum, d_out, flags);
}

// Round 9
// 1317.308 us; speedup vs baseline: 1.0713x; 1.0274x over previous
//
#include <hip/hip_runtime.h>
#include <hip/hip_bf16.h>

#define BATCH 512
#define SEQ   500
#define BS    (BATCH*SEQ)     // 256000
#define MEM   64
#define DK    128
#define DV    256
#define FC    128
#define PD    4               // scan prefetch depth (steps)

typedef float f32x4 __attribute__((ext_vector_type(4)));
typedef float f32x2 __attribute__((ext_vector_type(2)));
typedef unsigned short u16x8 __attribute__((ext_vector_type(8)));
typedef __bf16 bf16x8 __attribute__((ext_vector_type(8)));

typedef union { f32x4 v4; f32x2 v2[2]; } wpair_t;

__device__ __forceinline__ float bf2f(unsigned short u){ return __uint_as_float(((unsigned)u)<<16); }
__device__ __forceinline__ unsigned short f2bfu(float x){
  unsigned u = __float_as_uint(x);
  return (unsigned short)((u + 0x7FFFu + ((u>>16)&1u)) >> 16);  // RNE
}
__device__ __forceinline__ float sigf(float x){ return 1.f/(1.f+__expf(-x)); }
__device__ __forceinline__ float tanh_fast(float x){ return 2.f/(1.f+__expf(-2.f*x)) - 1.f; }

// packed dual-FMA (VOP3P): d = a*b + c, two f32 lanes per instruction
__device__ __forceinline__ f32x2 pk_fma(f32x2 a, f32x2 b, f32x2 c){
  f32x2 d;
  asm("v_pk_fma_f32 %0, %1, %2, %3" : "=v"(d) : "v"(a), "v"(b), "v"(c));
  return d;
}
__device__ __forceinline__ void pk_fma_acc(f32x2& d, f32x2 a, f32x2 b){
  asm("v_pk_fma_f32 %0, %1, %2, %0" : "+v"(d) : "v"(a), "v"(b));
}
__device__ __forceinline__ float swz_xor_add(float r, const int pat_sel){
  // pat_sel: 0 -> xor1, 1 -> xor2, 2 -> xor4 (BitMode patterns, 32-lane groups)
  int v;
  if (pat_sel == 0) v = __builtin_amdgcn_ds_swizzle(__builtin_bit_cast(int, r), 0x041F);
  else if (pat_sel == 1) v = __builtin_amdgcn_ds_swizzle(__builtin_bit_cast(int, r), 0x081F);
  else v = __builtin_amdgcn_ds_swizzle(__builtin_bit_cast(int, r), 0x101F);
  return r + __builtin_bit_cast(float, v);
}

__device__ __forceinline__ float ldF(const void* p, long i, int f32m){
  return f32m ? ((const float*)p)[i] : bf2f(((const unsigned short*)p)[i]);
}
__device__ __forceinline__ int ldI(const int* p, long i, int i64m){
  return i64m ? p[2*i] : p[i];   // little-endian low word of int64
}
__device__ __forceinline__ void st8(unsigned short* dst, const void* src, long i, int f32m){
  if (f32m){
    const float* q = (const float*)src + i;
    f32x4 a = *(const f32x4*)q;
    f32x4 b = *(const f32x4*)(q+4);
    u16x8 o;
    o[0]=f2bfu(a[0]); o[1]=f2bfu(a[1]); o[2]=f2bfu(a[2]); o[3]=f2bfu(a[3]);
    o[4]=f2bfu(b[0]); o[5]=f2bfu(b[1]); o[6]=f2bfu(b[2]); o[7]=f2bfu(b[3]);
    *(u16x8*)dst = o;
  } else {
    *(u16x8*)dst = *(const u16x8*)((const unsigned short*)src + i);
  }
}
__device__ __forceinline__ void stOut(void* p, long i, float x, int f32m){
  if (f32m) ((float*)p)[i] = x;
  else ((unsigned short*)p)[i] = f2bfu(x);
}

// ---------------- K0: dtype detection + accum zero ----------------
__global__ void k_detect(const unsigned short* __restrict__ km, const int* __restrict__ qa,
                         int* __restrict__ flags, float* __restrict__ accum){
  int t = threadIdx.x;            // 64 threads, one wave
  if (t < 2) accum[t] = 0.f;
  unsigned short u = km[2*t];     // even u16 halves of key_memory
  int e = (u >> 7) & 0xFF;
  bool sane = (e==0) || (e>=100 && e<=140);
  unsigned long long sm = __ballot(sane);
  unsigned long long zm = __ballot(qa[2*t+1] == 0);
  if (t == 0){
    flags[0] = (__popcll(sm) < 48) ? 1 : 0;               // 1 = f32 float buffers
    flags[1] = (zm == 0xFFFFFFFFFFFFFFFFull) ? 1 : 0;     // 1 = int64 index buffers
  }
}

// ---------------- K1: cw = softmax(q_e @ key^T) ----------------
__global__ __launch_bounds__(256, 2) void k_cw(const int* __restrict__ qd,
    const void* __restrict__ qW, const void* __restrict__ keym,
    float* __restrict__ cw, const int* __restrict__ flags){
  const int f32m = flags[0], i64m = flags[1];
  __shared__ float keyT[DK][MEM];
  int t = threadIdx.x;
  for (int i=t;i<MEM*DK;i+=256){ int m=i&63, k=i>>6; keyT[k][m] = ldF(keym, (long)m*DK+k, f32m); }
  __syncthreads();
  long row = (long)blockIdx.x*256 + t;
  int qid = ldI(qd, row, i64m);
  long qb = (long)qid*DK;
  f32x4 A[16];
  #pragma unroll
  for (int g=0;g<16;g++) A[g] = (f32x4){0.f,0.f,0.f,0.f};
  for (int kk=0;kk<DK;kk+=8){
    float qv[8];
    if (f32m){
      const float* qp = (const float*)qW + qb + kk;
      f32x4 a=*(const f32x4*)qp, b=*(const f32x4*)(qp+4);
      qv[0]=a[0];qv[1]=a[1];qv[2]=a[2];qv[3]=a[3];qv[4]=b[0];qv[5]=b[1];qv[6]=b[2];qv[7]=b[3];
    } else {
      u16x8 u = *(const u16x8*)((const unsigned short*)qW + qb + kk);
      #pragma unroll
      for (int j=0;j<8;j++) qv[j]=bf2f(u[j]);
    }
    #pragma unroll
    for (int j=0;j<8;j++){
      float q = qv[j];
      #pragma unroll
      for (int g=0;g<16;g++){
        f32x4 kv = *(const f32x4*)&keyT[kk+j][g*4];
        f32x4 a = A[g];
        a[0]=fmaf(q,kv[0],a[0]); a[1]=fmaf(q,kv[1],a[1]);
        a[2]=fmaf(q,kv[2],a[2]); a[3]=fmaf(q,kv[3],a[3]);
        A[g]=a;
      }
    }
  }
  float mx = -1e30f;
  #pragma unroll
  for (int g=0;g<16;g++){
    f32x4 a = A[g];
    mx = fmaxf(mx, fmaxf(fmaxf(a[0],a[1]), fmaxf(a[2],a[3])));
  }
  float sum = 0.f;
  #pragma unroll
  for (int g=0;g<16;g++){
    f32x4 a = A[g];
    a[0]=__expf(a[0]-mx); a[1]=__expf(a[1]-mx); a[2]=__expf(a[2]-mx); a[3]=__expf(a[3]-mx);
    sum += (a[0]+a[1])+(a[2]+a[3]);
    A[g]=a;
  }
  float inv = 1.f/sum;
  float* outp = cw + row*MEM;
  #pragma unroll
  for (int g=0;g<16;g++){
    f32x4 a = A[g];
    f32x4 v = { a[0]*inv, a[1]*inv, a[2]*inv, a[3]*inv };
    *(f32x4*)(outp + g*4) = v;
  }
}

// ---------------- K2 (per-chunk): [erase|add] -> interleaved (er[d],ad[d]) u16 pairs ----------------
__global__ __launch_bounds__(256, 2) void k_ea(const int* __restrict__ qad, long row0,
    const void* __restrict__ qaW, const void* __restrict__ eW, const void* __restrict__ ebias,
    const void* __restrict__ aW, const void* __restrict__ abias,
    unsigned short* __restrict__ ea, const int* __restrict__ flags){
  const int f32m = flags[0], i64m = flags[1];
  __shared__ unsigned short As[128][40];
  __shared__ unsigned short Bs[128][40];
  __shared__ int rid[128];
  int t = threadIdx.x;
  int bm = blockIdx.x, bn = blockIdx.y;
  if (t<128) rid[t] = ldI(qad, row0 + (long)bm*128+t, i64m);
  int lane = t & 63, wid = t >> 6;
  int wr = wid >> 1, wc = wid & 1;
  f32x4 acc[4][4] = {};
  for (int k0=0;k0<DV;k0+=32){
    __syncthreads();
    #pragma unroll
    for (int j=0;j<2;j++){
      int c = t*2+j, r = c>>2, ko = (c&3)*8;
      st8(&As[r][ko], qaW, (long)rid[r]*DV + k0 + ko, f32m);
      int gn = bn*128 + r;
      if (gn < DV) st8(&Bs[r][ko], eW, (long)gn*DV + k0 + ko, f32m);
      else         st8(&Bs[r][ko], aW, (long)(gn-DV)*DV + k0 + ko, f32m);
    }
    __syncthreads();
    bf16x8 af[4], bfr[4];
    #pragma unroll
    for (int i=0;i<4;i++){
      af[i]  = __builtin_bit_cast(bf16x8, *(const u16x8*)&As[wr*64+i*16+(lane&15)][(lane>>4)*8]);
      bfr[i] = __builtin_bit_cast(bf16x8, *(const u16x8*)&Bs[wc*64+i*16+(lane&15)][(lane>>4)*8]);
    }
    #pragma unroll
    for (int i=0;i<4;i++)
      #pragma unroll
      for (int n=0;n<4;n++)
        acc[i][n] = __builtin_amdgcn_mfma_f32_16x16x32_bf16(af[i], bfr[n], acc[i][n],0,0,0);
  }
  #pragma unroll
  for (int i=0;i<4;i++)
    #pragma unroll
    for (int n=0;n<4;n++){
      int col = bn*128 + wc*64 + n*16 + (lane&15);
      float bias = (col<DV) ? ldF(ebias,col,f32m) : ldF(abias,col-DV,f32m);
      int dcol = (col<DV) ? 2*col : 2*(col-DV)+1;   // interleaved pair layout
      #pragma unroll
      for (int rix=0;rix<4;rix++){
        long rowg = (long)bm*128 + wr*64 + i*16 + (lane>>4)*4 + rix;
        float v = acc[i][n][rix] + bias;
        float o = (col<DV) ? sigf(v) : tanh_fast(v);
        ea[rowg*(2*DV) + dcol] = f2bfu(o);
      }
    }
}

// ---------------- K3 (per-chunk): scan, m split 8-ways, pk_fma + ds_swizzle ----------------
// thread (d, q=tid&7) owns m in [8q, 8q+8)
// update: m_new = m + w*(ad - m*er)  (== m*(1-w*er) + w*ad)
#define SCAN_STEP(WP, U, RDOFF) { \
  float er = bf2f((unsigned short)((U) & 0xFFFFu)); \
  float ad = bf2f((unsigned short)((U) >> 16)); \
  float ner = -er; \
  f32x2 ner2 = {ner, ner}; \
  f32x2 ad2  = {ad, ad}; \
  f32x2 r2 = {0.f, 0.f}; \
  _Pragma("unroll") \
  for (int jj=0; jj<4; jj++){ \
    f32x2 w2 = (jj<2) ? WP[0].v2[jj] : WP[1].v2[jj-2]; \
    pk_fma_acc(r2, w2, M2[jj]); \
    f32x2 tt2 = pk_fma(M2[jj], ner2, ad2); \
    pk_fma_acc(M2[jj], w2, tt2); \
  } \
  float r = r2[0] + r2[1]; \
  r = swz_xor_add(r, 0); \
  r = swz_xor_add(r, 1); \
  r = swz_xor_add(r, 2); \
  if (q == 0) rdp[RDOFF] = f2bfu(r); \
}

__global__ __launch_bounds__(1024, 8) void k_scan(const float* __restrict__ cw,
    const unsigned short* __restrict__ ea, const void* __restrict__ initm,
    unsigned short* __restrict__ rdout, const int* __restrict__ flags){
  const int f32m = flags[0];
  int b = blockIdx.x;
  int t = threadIdx.x;
  int q = t & 7;
  int d = (int)blockIdx.y*128 + (t >> 3);
  int m0 = q * 8;
  f32x2 M2[4];
  #pragma unroll
  for (int g=0; g<4; g++){
    f32x2 v;
    v[0] = ldF(initm, (long)(m0+2*g+0)*DV + d, f32m);
    v[1] = ldF(initm, (long)(m0+2*g+1)*DV + d, f32m);
    M2[g] = v;
  }
  const float* wp = cw + (long)b*SEQ*MEM + m0;
  const unsigned int* ep = (const unsigned int*)(ea + (long)b*SEQ*(2*DV)) + d;  // 256 u32/row
  unsigned short* rdp = rdout + (long)b*SEQ*DV + d;

  wpair_t W[PD][2];
  unsigned int U[PD];
  #pragma unroll
  for (int i=0;i<PD;i++){
    W[i][0].v4 = *(const f32x4*)(wp + i*MEM);
    W[i][1].v4 = *(const f32x4*)(wp + i*MEM + 4);
    U[i]  = ep[i*256];
  }
  // main: steps 0..SEQ-PD-1 with PD-deep prefetch
  for (int s=0; s<SEQ-PD; s+=PD){
    #pragma unroll
    for (int i=0;i<PD;i++){
      SCAN_STEP(W[i], U[i], i*DV);
      // prefetch step s+PD+i (over-read past batch end stays inside ws; unused)
      W[i][0].v4 = *(const f32x4*)(wp + (PD+i)*MEM);
      W[i][1].v4 = *(const f32x4*)(wp + (PD+i)*MEM + 4);
      U[i]  = ep[(PD+i)*256];
    }
    wp += PD*MEM; ep += PD*256; rdp += PD*DV;
  }
  // tail: last PD steps, no prefetch
  #pragma unroll
  for (int i=0;i<PD;i++){
    SCAN_STEP(W[i], U[i], i*DV);
  }
}

// ---------------- K4 (per-chunk): h = tanh([reads|q_e] @ rW^T + rb); logit; BCE ----------------
__global__ __launch_bounds__(256, 2) void k_pred(const int* __restrict__ qd, long row0,
    const void* __restrict__ qW, const unsigned short* __restrict__ rds,
    const void* __restrict__ rW, const void* __restrict__ rb,
    const void* __restrict__ pW, const void* __restrict__ pb,
    const void* __restrict__ target,
    void* __restrict__ out, float* __restrict__ accum,
    const int* __restrict__ flags){
  const int f32m = flags[0], i64m = flags[1];
  __shared__ unsigned short As[128][40];
  __shared__ unsigned short Bs[128][40];
  __shared__ unsigned short hs[128][136];
  __shared__ int rid[128];
  int t = threadIdx.x;
  int bm = blockIdx.x;
  if (t<128) rid[t] = ldI(qd, row0 + (long)bm*128+t, i64m);
  int lane=t&63, wid=t>>6, wr=wid>>1, wc=wid&1;
  f32x4 acc[4][4] = {};
  for (int k0=0;k0<(DV+DK);k0+=32){
    __syncthreads();
    #pragma unroll
    for (int j=0;j<2;j++){
      int c=t*2+j, r=c>>2, ko=(c&3)*8;
      if (k0 < DV) st8(&As[r][ko], rds, ((long)bm*128+r)*DV + k0+ko, 0);
      else         st8(&As[r][ko], qW, (long)rid[r]*DK + (k0-DV)+ko, f32m);
      st8(&Bs[r][ko], rW, (long)r*(DV+DK) + k0+ko, f32m);
    }
    __syncthreads();
    bf16x8 af[4], bfr[4];
    #pragma unroll
    for (int i=0;i<4;i++){
      af[i]  = __builtin_bit_cast(bf16x8, *(const u16x8*)&As[wr*64+i*16+(lane&15)][(lane>>4)*8]);
      bfr[i] = __builtin_bit_cast(bf16x8, *(const u16x8*)&Bs[wc*64+i*16+(lane&15)][(lane>>4)*8]);
    }
    #pragma unroll
    for (int i=0;i<4;i++)
      #pragma unroll
      for (int n=0;n<4;n++)
        acc[i][n] = __builtin_amdgcn_mfma_f32_16x16x32_bf16(af[i], bfr[n], acc[i][n],0,0,0);
  }
  #pragma unroll
  for (int i=0;i<4;i++)
    #pragma unroll
    for (int n=0;n<4;n++){
      int col = wc*64 + n*16 + (lane&15);
      float bias = ldF(rb, col, f32m);
      #pragma unroll
      for (int rix=0;rix<4;rix++){
        int rowl = wr*64 + i*16 + (lane>>4)*4 + rix;
        hs[rowl][col] = f2bfu(tanh_fast(acc[i][n][rix] + bias));
      }
    }
  __syncthreads();
  float bces = 0.f, cnts = 0.f;
  if (t < 128){
    float lg = ldF(pb, 0, f32m);
    #pragma unroll
    for (int cc=0;cc<FC;cc++) lg = fmaf(bf2f(hs[t][cc]), ldF(pW, cc, f32m), lg);
    long rowg = row0 + (long)bm*128 + t;
    float tg = ldF(target, rowg, f32m);
    bool mask = tg >= 0.f;
    float e = __expf(-fabsf(lg));
    float bce = fmaxf(lg, 0.f) - lg*tg + __logf(1.f + e);
    bces = mask ? bce : 0.f;
    cnts = mask ? 1.f : 0.f;
    stOut(out, 1 + rowg, mask ? sigf(lg) : 0.f, f32m);
    stOut(out, 1 + BS + rowg, mask ? tg : 0.f, f32m);
  }
  #pragma unroll
  for (int off=32; off>0; off>>=1){ bces += __shfl_down(bces, off); cnts += __shfl_down(cnts, off); }
  if ((t & 63) == 0 && t < 128){
    atomicAdd(&accum[0], bces);
    atomicAdd(&accum[1], cnts);
  }
}

__global__ void k_loss(const float* __restrict__ accum, void* __restrict__ out,
                       const int* __restrict__ flags){
  if (threadIdx.x == 0){
    float denom = fmaxf(accum[1], 1.f);
    stOut(out, 0, accum[0]/denom, flags[0]);
  }
}

extern "C" void kernel_launch(void* const* d_in, const int* in_sizes, int n_in,
                              void* d_out, int out_size, void* d_ws, size_t ws_size,
                              hipStream_t stream) {
  const int* q_data  = (const int*)d_in[0];
  const int* qa_data = (const int*)d_in[1];
  const void* target = d_in[2];
  const void* qW   = d_in[3];
  const void* qaW  = d_in[4];
  const void* keym = d_in[5];
  const void* initm= d_in[6];
  const void* eW   = d_in[7];
  const void* eb   = d_in[8];
  const void* aW   = d_in[9];
  const void* ab   = d_in[10];
  const void* rW   = d_in[11];
  const void* rb   = d_in[12];
  const void* pW   = d_in[13];
  const void* pb   = d_in[14];

  char* ws = (char*)d_ws;
  const size_t CW_OFF = 256;
  const size_t CW_BYTES = (size_t)BS*MEM*4;              // 65,536,000
  const size_t EA_OFF = CW_OFF + CW_BYTES;
  float* accum = (float*)ws;
  int* flags = (int*)(ws + 64);
  float* cw = (float*)(ws + CW_OFF);

  const long per_batch = (long)SEQ*(2*DV)*2 + (long)SEQ*DV*2;  // 768000 B per batch
  long rem = (long)ws_size - (long)EA_OFF;
  int bchunk = 512;
  while (bchunk > 32 && per_batch*bchunk > rem) bchunk >>= 1;  // 512,256,128,64,32

  const size_t EA_BYTES = (size_t)bchunk*SEQ*(2*DV)*2;
  unsigned short* ea = (unsigned short*)(ws + EA_OFF);
  unsigned short* rd = (unsigned short*)(ws + EA_OFF + EA_BYTES);

  k_detect<<<1, 64, 0, stream>>>((const unsigned short*)keym, qa_data, flags, accum);
  k_cw  <<<BS/256, 256, 0, stream>>>(q_data, qW, keym, cw, flags);

  int nchunk = BATCH / bchunk;
  for (int c = 0; c < nchunk; c++){
    long b0 = (long)c * bchunk;
    int rows = bchunk * SEQ;
    k_ea  <<<dim3(rows/128, 4), 256, 0, stream>>>(qa_data, b0*SEQ, qaW, eW, eb, aW, ab, ea, flags);
    k_scan<<<dim3(bchunk, 2), 1024, 0, stream>>>(cw + b0*SEQ*MEM, ea, initm, rd, flags);
    k_pred<<<rows/128, 256, 0, stream>>>(q_data, b0*SEQ, qW, rd, rW, rb, pW, pb,
                                         target, d_out, accum, flags);
  }
  k_loss<<<1, 64, 0, stream>>>(accum, d_out, flags);
}

// Round 10
// 1306.801 us; speedup vs baseline: 1.0800x; 1.0080x over previous
//
#include <hip/hip_runtime.h>
#include <hip/hip_bf16.h>

#define BATCH 512
#define SEQ   500
#define BS    (BATCH*SEQ)     // 256000
#define MEM   64
#define DK    128
#define DV    256
#define FC    128
#define PD    4               // scan prefetch depth (steps)

typedef float f32x4 __attribute__((ext_vector_type(4)));
typedef float f32x2 __attribute__((ext_vector_type(2)));
typedef unsigned short u16x8 __attribute__((ext_vector_type(8)));
typedef __bf16 bf16x8 __attribute__((ext_vector_type(8)));

typedef union { f32x4 v4; f32x2 v2[2]; } wpair_t;

__device__ __forceinline__ float bf2f(unsigned short u){ return __uint_as_float(((unsigned)u)<<16); }
__device__ __forceinline__ unsigned short f2bfu(float x){
  unsigned u = __float_as_uint(x);
  return (unsigned short)((u + 0x7FFFu + ((u>>16)&1u)) >> 16);  // RNE
}
__device__ __forceinline__ float sigf(float x){ return 1.f/(1.f+__expf(-x)); }
__device__ __forceinline__ float tanh_fast(float x){ return 2.f/(1.f+__expf(-2.f*x)) - 1.f; }

// packed dual-FMA (VOP3P): d = a*b + c, two f32 lanes per instruction
__device__ __forceinline__ f32x2 pk_fma(f32x2 a, f32x2 b, f32x2 c){
  f32x2 d;
  asm("v_pk_fma_f32 %0, %1, %2, %3" : "=v"(d) : "v"(a), "v"(b), "v"(c));
  return d;
}
__device__ __forceinline__ void pk_fma_acc(f32x2& d, f32x2 a, f32x2 b){
  asm("v_pk_fma_f32 %0, %1, %2, %0" : "+v"(d) : "v"(a), "v"(b));
}
// DPP row-shift add: r += r shifted by N lanes within the 16-lane row (zero-fill).
// After shr:1, shr:2, shr:4 the sum of each 8-lane group lands in its highest lane (q==7).
#define DPP_ADD(r, ctrl) { \
  int _s = __builtin_amdgcn_update_dpp(0, __builtin_bit_cast(int, r), ctrl, 0xF, 0xF, true); \
  r += __builtin_bit_cast(float, _s); \
}

__device__ __forceinline__ float ldF(const void* p, long i, int f32m){
  return f32m ? ((const float*)p)[i] : bf2f(((const unsigned short*)p)[i]);
}
__device__ __forceinline__ int ldI(const int* p, long i, int i64m){
  return i64m ? p[2*i] : p[i];   // little-endian low word of int64
}
__device__ __forceinline__ void st8(unsigned short* dst, const void* src, long i, int f32m){
  if (f32m){
    const float* q = (const float*)src + i;
    f32x4 a = *(const f32x4*)q;
    f32x4 b = *(const f32x4*)(q+4);
    u16x8 o;
    o[0]=f2bfu(a[0]); o[1]=f2bfu(a[1]); o[2]=f2bfu(a[2]); o[3]=f2bfu(a[3]);
    o[4]=f2bfu(b[0]); o[5]=f2bfu(b[1]); o[6]=f2bfu(b[2]); o[7]=f2bfu(b[3]);
    *(u16x8*)dst = o;
  } else {
    *(u16x8*)dst = *(const u16x8*)((const unsigned short*)src + i);
  }
}
__device__ __forceinline__ void stOut(void* p, long i, float x, int f32m){
  if (f32m) ((float*)p)[i] = x;
  else ((unsigned short*)p)[i] = f2bfu(x);
}

// ---------------- K0: dtype detection + accum zero ----------------
__global__ void k_detect(const unsigned short* __restrict__ km, const int* __restrict__ qa,
                         int* __restrict__ flags, float* __restrict__ accum){
  int t = threadIdx.x;            // 64 threads, one wave
  if (t < 2) accum[t] = 0.f;
  unsigned short u = km[2*t];     // even u16 halves of key_memory
  int e = (u >> 7) & 0xFF;
  bool sane = (e==0) || (e>=100 && e<=140);
  unsigned long long sm = __ballot(sane);
  unsigned long long zm = __ballot(qa[2*t+1] == 0);
  if (t == 0){
    flags[0] = (__popcll(sm) < 48) ? 1 : 0;               // 1 = f32 float buffers
    flags[1] = (zm == 0xFFFFFFFFFFFFFFFFull) ? 1 : 0;     // 1 = int64 index buffers
  }
}

// ---------------- K1: cw = softmax(q_e @ key^T) ----------------
__global__ __launch_bounds__(256, 2) void k_cw(const int* __restrict__ qd,
    const void* __restrict__ qW, const void* __restrict__ keym,
    float* __restrict__ cw, const int* __restrict__ flags){
  const int f32m = flags[0], i64m = flags[1];
  __shared__ float keyT[DK][MEM];
  int t = threadIdx.x;
  for (int i=t;i<MEM*DK;i+=256){ int m=i&63, k=i>>6; keyT[k][m] = ldF(keym, (long)m*DK+k, f32m); }
  __syncthreads();
  long row = (long)blockIdx.x*256 + t;
  int qid = ldI(qd, row, i64m);
  long qb = (long)qid*DK;
  f32x4 A[16];
  #pragma unroll
  for (int g=0;g<16;g++) A[g] = (f32x4){0.f,0.f,0.f,0.f};
  for (int kk=0;kk<DK;kk+=8){
    float qv[8];
    if (f32m){
      const float* qp = (const float*)qW + qb + kk;
      f32x4 a=*(const f32x4*)qp, b=*(const f32x4*)(qp+4);
      qv[0]=a[0];qv[1]=a[1];qv[2]=a[2];qv[3]=a[3];qv[4]=b[0];qv[5]=b[1];qv[6]=b[2];qv[7]=b[3];
    } else {
      u16x8 u = *(const u16x8*)((const unsigned short*)qW + qb + kk);
      #pragma unroll
      for (int j=0;j<8;j++) qv[j]=bf2f(u[j]);
    }
    #pragma unroll
    for (int j=0;j<8;j++){
      float q = qv[j];
      #pragma unroll
      for (int g=0;g<16;g++){
        f32x4 kv = *(const f32x4*)&keyT[kk+j][g*4];
        f32x4 a = A[g];
        a[0]=fmaf(q,kv[0],a[0]); a[1]=fmaf(q,kv[1],a[1]);
        a[2]=fmaf(q,kv[2],a[2]); a[3]=fmaf(q,kv[3],a[3]);
        A[g]=a;
      }
    }
  }
  float mx = -1e30f;
  #pragma unroll
  for (int g=0;g<16;g++){
    f32x4 a = A[g];
    mx = fmaxf(mx, fmaxf(fmaxf(a[0],a[1]), fmaxf(a[2],a[3])));
  }
  float sum = 0.f;
  #pragma unroll
  for (int g=0;g<16;g++){
    f32x4 a = A[g];
    a[0]=__expf(a[0]-mx); a[1]=__expf(a[1]-mx); a[2]=__expf(a[2]-mx); a[3]=__expf(a[3]-mx);
    sum += (a[0]+a[1])+(a[2]+a[3]);
    A[g]=a;
  }
  float inv = 1.f/sum;
  float* outp = cw + row*MEM;
  #pragma unroll
  for (int g=0;g<16;g++){
    f32x4 a = A[g];
    f32x4 v = { a[0]*inv, a[1]*inv, a[2]*inv, a[3]*inv };
    *(f32x4*)(outp + g*4) = v;
  }
}

// ---------------- K2 (per-chunk): [erase|add] -> interleaved (er[d],ad[d]) u16 pairs ----------------
__global__ __launch_bounds__(256, 2) void k_ea(const int* __restrict__ qad, long row0,
    const void* __restrict__ qaW, const void* __restrict__ eW, const void* __restrict__ ebias,
    const void* __restrict__ aW, const void* __restrict__ abias,
    unsigned short* __restrict__ ea, const int* __restrict__ flags){
  const int f32m = flags[0], i64m = flags[1];
  __shared__ unsigned short As[128][40];
  __shared__ unsigned short Bs[128][40];
  __shared__ int rid[128];
  int t = threadIdx.x;
  int bm = blockIdx.x, bn = blockIdx.y;
  if (t<128) rid[t] = ldI(qad, row0 + (long)bm*128+t, i64m);
  int lane = t & 63, wid = t >> 6;
  int wr = wid >> 1, wc = wid & 1;
  f32x4 acc[4][4] = {};
  for (int k0=0;k0<DV;k0+=32){
    __syncthreads();
    #pragma unroll
    for (int j=0;j<2;j++){
      int c = t*2+j, r = c>>2, ko = (c&3)*8;
      st8(&As[r][ko], qaW, (long)rid[r]*DV + k0 + ko, f32m);
      int gn = bn*128 + r;
      if (gn < DV) st8(&Bs[r][ko], eW, (long)gn*DV + k0 + ko, f32m);
      else         st8(&Bs[r][ko], aW, (long)(gn-DV)*DV + k0 + ko, f32m);
    }
    __syncthreads();
    bf16x8 af[4], bfr[4];
    #pragma unroll
    for (int i=0;i<4;i++){
      af[i]  = __builtin_bit_cast(bf16x8, *(const u16x8*)&As[wr*64+i*16+(lane&15)][(lane>>4)*8]);
      bfr[i] = __builtin_bit_cast(bf16x8, *(const u16x8*)&Bs[wc*64+i*16+(lane&15)][(lane>>4)*8]);
    }
    #pragma unroll
    for (int i=0;i<4;i++)
      #pragma unroll
      for (int n=0;n<4;n++)
        acc[i][n] = __builtin_amdgcn_mfma_f32_16x16x32_bf16(af[i], bfr[n], acc[i][n],0,0,0);
  }
  #pragma unroll
  for (int i=0;i<4;i++)
    #pragma unroll
    for (int n=0;n<4;n++){
      int col = bn*128 + wc*64 + n*16 + (lane&15);
      float bias = (col<DV) ? ldF(ebias,col,f32m) : ldF(abias,col-DV,f32m);
      int dcol = (col<DV) ? 2*col : 2*(col-DV)+1;   // interleaved pair layout
      #pragma unroll
      for (int rix=0;rix<4;rix++){
        long rowg = (long)bm*128 + wr*64 + i*16 + (lane>>4)*4 + rix;
        float v = acc[i][n][rix] + bias;
        float o = (col<DV) ? sigf(v) : tanh_fast(v);
        ea[rowg*(2*DV) + dcol] = f2bfu(o);
      }
    }
}

// ---------------- K3 (per-chunk): scan, m split 8-ways, pk_fma + DPP reduce ----------------
// thread (d, q=tid&7) owns m in [8q, 8q+8)
// update: m_new = m + w*(ad - m*er)  (== m*(1-w*er) + w*ad)
// reduce: row_shr 1/2/4 DPP adds put the 8-lane group sum in lane q==7
#define SCAN_STEP(WP, U, RDOFF) { \
  float er = bf2f((unsigned short)((U) & 0xFFFFu)); \
  float ad = bf2f((unsigned short)((U) >> 16)); \
  float ner = -er; \
  f32x2 ner2 = {ner, ner}; \
  f32x2 ad2  = {ad, ad}; \
  f32x2 r2 = {0.f, 0.f}; \
  _Pragma("unroll") \
  for (int jj=0; jj<4; jj++){ \
    f32x2 w2 = (jj<2) ? WP[0].v2[jj] : WP[1].v2[jj-2]; \
    pk_fma_acc(r2, w2, M2[jj]); \
    f32x2 tt2 = pk_fma(M2[jj], ner2, ad2); \
    pk_fma_acc(M2[jj], w2, tt2); \
  } \
  float r = r2[0] + r2[1]; \
  DPP_ADD(r, 0x111); \
  DPP_ADD(r, 0x112); \
  DPP_ADD(r, 0x114); \
  if (q == 7) rdp[RDOFF] = f2bfu(r); \
}

__global__ __launch_bounds__(1024, 8) void k_scan(const float* __restrict__ cw,
    const unsigned short* __restrict__ ea, const void* __restrict__ initm,
    unsigned short* __restrict__ rdout, const int* __restrict__ flags){
  const int f32m = flags[0];
  int b = blockIdx.x;
  int t = threadIdx.x;
  int q = t & 7;
  int d = (int)blockIdx.y*128 + (t >> 3);
  int m0 = q * 8;
  f32x2 M2[4];
  #pragma unroll
  for (int g=0; g<4; g++){
    f32x2 v;
    v[0] = ldF(initm, (long)(m0+2*g+0)*DV + d, f32m);
    v[1] = ldF(initm, (long)(m0+2*g+1)*DV + d, f32m);
    M2[g] = v;
  }
  const float* wp = cw + (long)b*SEQ*MEM + m0;
  const unsigned int* ep = (const unsigned int*)(ea + (long)b*SEQ*(2*DV)) + d;  // 256 u32/row
  unsigned short* rdp = rdout + (long)b*SEQ*DV + d;

  wpair_t W[PD][2];
  unsigned int U[PD];
  #pragma unroll
  for (int i=0;i<PD;i++){
    W[i][0].v4 = *(const f32x4*)(wp + i*MEM);
    W[i][1].v4 = *(const f32x4*)(wp + i*MEM + 4);
    U[i]  = ep[i*256];
  }
  // main: steps 0..SEQ-PD-1 with PD-deep prefetch
  for (int s=0; s<SEQ-PD; s+=PD){
    #pragma unroll
    for (int i=0;i<PD;i++){
      SCAN_STEP(W[i], U[i], i*DV);
      // prefetch step s+PD+i (over-read past batch end stays inside ws; unused)
      W[i][0].v4 = *(const f32x4*)(wp + (PD+i)*MEM);
      W[i][1].v4 = *(const f32x4*)(wp + (PD+i)*MEM + 4);
      U[i]  = ep[(PD+i)*256];
    }
    wp += PD*MEM; ep += PD*256; rdp += PD*DV;
  }
  // tail: last PD steps, no prefetch
  #pragma unroll
  for (int i=0;i<PD;i++){
    SCAN_STEP(W[i], U[i], i*DV);
  }
}

// ---------------- K4 (per-chunk): h = tanh([reads|q_e] @ rW^T + rb); logit; BCE ----------------
__global__ __launch_bounds__(256, 2) void k_pred(const int* __restrict__ qd, long row0,
    const void* __restrict__ qW, const unsigned short* __restrict__ rds,
    const void* __restrict__ rW, const void* __restrict__ rb,
    const void* __restrict__ pW, const void* __restrict__ pb,
    const void* __restrict__ target,
    void* __restrict__ out, float* __restrict__ accum,
    const int* __restrict__ flags){
  const int f32m = flags[0], i64m = flags[1];
  __shared__ unsigned short As[128][40];
  __shared__ unsigned short Bs[128][40];
  __shared__ unsigned short hs[128][136];
  __shared__ int rid[128];
  int t = threadIdx.x;
  int bm = blockIdx.x;
  if (t<128) rid[t] = ldI(qd, row0 + (long)bm*128+t, i64m);
  int lane=t&63, wid=t>>6, wr=wid>>1, wc=wid&1;
  f32x4 acc[4][4] = {};
  for (int k0=0;k0<(DV+DK);k0+=32){
    __syncthreads();
    #pragma unroll
    for (int j=0;j<2;j++){
      int c=t*2+j, r=c>>2, ko=(c&3)*8;
      if (k0 < DV) st8(&As[r][ko], rds, ((long)bm*128+r)*DV + k0+ko, 0);
      else         st8(&As[r][ko], qW, (long)rid[r]*DK + (k0-DV)+ko, f32m);
      st8(&Bs[r][ko], rW, (long)r*(DV+DK) + k0+ko, f32m);
    }
    __syncthreads();
    bf16x8 af[4], bfr[4];
    #pragma unroll
    for (int i=0;i<4;i++){
      af[i]  = __builtin_bit_cast(bf16x8, *(const u16x8*)&As[wr*64+i*16+(lane&15)][(lane>>4)*8]);
      bfr[i] = __builtin_bit_cast(bf16x8, *(const u16x8*)&Bs[wc*64+i*16+(lane&15)][(lane>>4)*8]);
    }
    #pragma unroll
    for (int i=0;i<4;i++)
      #pragma unroll
      for (int n=0;n<4;n++)
        acc[i][n] = __builtin_amdgcn_mfma_f32_16x16x32_bf16(af[i], bfr[n], acc[i][n],0,0,0);
  }
  #pragma unroll
  for (int i=0;i<4;i++)
    #pragma unroll
    for (int n=0;n<4;n++){
      int col = wc*64 + n*16 + (lane&15);
      float bias = ldF(rb, col, f32m);
      #pragma unroll
      for (int rix=0;rix<4;rix++){
        int rowl = wr*64 + i*16 + (lane>>4)*4 + rix;
        hs[rowl][col] = f2bfu(tanh_fast(acc[i][n][rix] + bias));
      }
    }
  __syncthreads();
  float bces = 0.f, cnts = 0.f;
  if (t < 128){
    float lg = ldF(pb, 0, f32m);
    #pragma unroll
    for (int cc=0;cc<FC;cc++) lg = fmaf(bf2f(hs[t][cc]), ldF(pW, cc, f32m), lg);
    long rowg = row0 + (long)bm*128 + t;
    float tg = ldF(target, rowg, f32m);
    bool mask = tg >= 0.f;
    float e = __expf(-fabsf(lg));
    float bce = fmaxf(lg, 0.f) - lg*tg + __logf(1.f + e);
    bces = mask ? bce : 0.f;
    cnts = mask ? 1.f : 0.f;
    stOut(out, 1 + rowg, mask ? sigf(lg) : 0.f, f32m);
    stOut(out, 1 + BS + rowg, mask ? tg : 0.f, f32m);
  }
  #pragma unroll
  for (int off=32; off>0; off>>=1){ bces += __shfl_down(bces, off); cnts += __shfl_down(cnts, off); }
  if ((t & 63) == 0 && t < 128){
    atomicAdd(&accum[0], bces);
    atomicAdd(&accum[1], cnts);
  }
}

__global__ void k_loss(const float* __restrict__ accum, void* __restrict__ out,
                       const int* __restrict__ flags){
  if (threadIdx.x == 0){
    float denom = fmaxf(accum[1], 1.f);
    stOut(out, 0, accum[0]/denom, flags[0]);
  }
}

extern "C" void kernel_launch(void* const* d_in, const int* in_sizes, int n_in,
                              void* d_out, int out_size, void* d_ws, size_t ws_size,
                              hipStream_t stream) {
  const int* q_data  = (const int*)d_in[0];
  const int* qa_data = (const int*)d_in[1];
  const void* target = d_in[2];
  const void* qW   = d_in[3];
  const void* qaW  = d_in[4];
  const void* keym = d_in[5];
  const void* initm= d_in[6];
  const void* eW   = d_in[7];
  const void* eb   = d_in[8];
  const void* aW   = d_in[9];
  const void* ab   = d_in[10];
  const void* rW   = d_in[11];
  const void* rb   = d_in[12];
  const void* pW   = d_in[13];
  const void* pb   = d_in[14];

  char* ws = (char*)d_ws;
  const size_t CW_OFF = 256;
  const size_t CW_BYTES = (size_t)BS*MEM*4;              // 65,536,000
  const size_t EA_OFF = CW_OFF + CW_BYTES;
  float* accum = (float*)ws;
  int* flags = (int*)(ws + 64);
  float* cw = (float*)(ws + CW_OFF);

  const long per_batch = (long)SEQ*(2*DV)*2 + (long)SEQ*DV*2;  // 768000 B per batch
  long rem = (long)ws_size - (long)EA_OFF;
  int bchunk = 512;
  while (bchunk > 32 && per_batch*bchunk > rem) bchunk >>= 1;  // 512,256,128,64,32

  const size_t EA_BYTES = (size_t)bchunk*SEQ*(2*DV)*2;
  unsigned short* ea = (unsigned short*)(ws + EA_OFF);
  unsigned short* rd = (unsigned short*)(ws + EA_OFF + EA_BYTES);

  k_detect<<<1, 64, 0, stream>>>((const unsigned short*)keym, qa_data, flags, accum);
  k_cw  <<<BS/256, 256, 0, stream>>>(q_data, qW, keym, cw, flags);

  int nchunk = BATCH / bchunk;
  for (int c = 0; c < nchunk; c++){
    long b0 = (long)c * bchunk;
    int rows = bchunk * SEQ;
    k_ea  <<<dim3(rows/128, 4), 256, 0, stream>>>(qa_data, b0*SEQ, qaW, eW, eb, aW, ab, ea, flags);
    k_scan<<<dim3(bchunk, 2), 1024, 0, stream>>>(cw + b0*SEQ*MEM, ea, initm, rd, flags);
    k_pred<<<rows/128, 256, 0, stream>>>(q_data, b0*SEQ, qW, rd, rW, rb, pW, pb,
                                         target, d_out, accum, flags);
  }
  k_loss<<<1, 64, 0, stream>>>(accum, d_out, flags);
}

// Round 11
// 1133.362 us; speedup vs baseline: 1.2452x; 1.1530x over previous
//
#include <hip/hip_runtime.h>
#include <hip/hip_bf16.h>

#define BATCH 512
#define SEQ   500
#define BS    (BATCH*SEQ)     // 256000
#define MEM   64
#define DK    128
#define DV    256
#define FC    128
#define KS    16              // scan steps per LDS stage

typedef float f32x4 __attribute__((ext_vector_type(4)));
typedef float f32x2 __attribute__((ext_vector_type(2)));
typedef unsigned int u32x4 __attribute__((ext_vector_type(4)));
typedef unsigned int u32x2 __attribute__((ext_vector_type(2)));
typedef unsigned short u16x8 __attribute__((ext_vector_type(8)));
typedef __bf16 bf16x8 __attribute__((ext_vector_type(8)));

typedef union { f32x4 v4; f32x2 v2[2]; } wpair_t;

__device__ __forceinline__ float bf2f(unsigned short u){ return __uint_as_float(((unsigned)u)<<16); }
__device__ __forceinline__ unsigned short f2bfu(float x){
  unsigned u = __float_as_uint(x);
  return (unsigned short)((u + 0x7FFFu + ((u>>16)&1u)) >> 16);  // RNE
}
__device__ __forceinline__ float sigf(float x){ return 1.f/(1.f+__expf(-x)); }
__device__ __forceinline__ float tanh_fast(float x){ return 2.f/(1.f+__expf(-2.f*x)) - 1.f; }

// packed dual-FMA (VOP3P): d = a*b + c, two f32 lanes per instruction
__device__ __forceinline__ f32x2 pk_fma(f32x2 a, f32x2 b, f32x2 c){
  f32x2 d;
  asm("v_pk_fma_f32 %0, %1, %2, %3" : "=v"(d) : "v"(a), "v"(b), "v"(c));
  return d;
}
__device__ __forceinline__ void pk_fma_acc(f32x2& d, f32x2 a, f32x2 b){
  asm("v_pk_fma_f32 %0, %1, %2, %0" : "+v"(d) : "v"(a), "v"(b));
}
// DPP row-shift add: after shr:1, shr:2, shr:4 the 8-lane-group sum lands in lane q==7.
#define DPP_ADD(r, ctrl) { \
  int _s = __builtin_amdgcn_update_dpp(0, __builtin_bit_cast(int, r), ctrl, 0xF, 0xF, true); \
  r += __builtin_bit_cast(float, _s); \
}

__device__ __forceinline__ float ldF(const void* p, long i, int f32m){
  return f32m ? ((const float*)p)[i] : bf2f(((const unsigned short*)p)[i]);
}
__device__ __forceinline__ int ldI(const int* p, long i, int i64m){
  return i64m ? p[2*i] : p[i];   // little-endian low word of int64
}
__device__ __forceinline__ void st8(unsigned short* dst, const void* src, long i, int f32m){
  if (f32m){
    const float* q = (const float*)src + i;
    f32x4 a = *(const f32x4*)q;
    f32x4 b = *(const f32x4*)(q+4);
    u16x8 o;
    o[0]=f2bfu(a[0]); o[1]=f2bfu(a[1]); o[2]=f2bfu(a[2]); o[3]=f2bfu(a[3]);
    o[4]=f2bfu(b[0]); o[5]=f2bfu(b[1]); o[6]=f2bfu(b[2]); o[7]=f2bfu(b[3]);
    *(u16x8*)dst = o;
  } else {
    *(u16x8*)dst = *(const u16x8*)((const unsigned short*)src + i);
  }
}
__device__ __forceinline__ void stOut(void* p, long i, float x, int f32m){
  if (f32m) ((float*)p)[i] = x;
  else ((unsigned short*)p)[i] = f2bfu(x);
}

// ---------------- K0: dtype detection + accum zero ----------------
__global__ void k_detect(const unsigned short* __restrict__ km, const int* __restrict__ qa,
                         int* __restrict__ flags, float* __restrict__ accum){
  int t = threadIdx.x;            // 64 threads, one wave
  if (t < 2) accum[t] = 0.f;
  unsigned short u = km[2*t];     // even u16 halves of key_memory
  int e = (u >> 7) & 0xFF;
  bool sane = (e==0) || (e>=100 && e<=140);
  unsigned long long sm = __ballot(sane);
  unsigned long long zm = __ballot(qa[2*t+1] == 0);
  if (t == 0){
    flags[0] = (__popcll(sm) < 48) ? 1 : 0;               // 1 = f32 float buffers
    flags[1] = (zm == 0xFFFFFFFFFFFFFFFFull) ? 1 : 0;     // 1 = int64 index buffers
  }
}

// ---------------- K1: cw = softmax(q_e @ key^T) ----------------
__global__ __launch_bounds__(256, 2) void k_cw(const int* __restrict__ qd,
    const void* __restrict__ qW, const void* __restrict__ keym,
    float* __restrict__ cw, const int* __restrict__ flags){
  const int f32m = flags[0], i64m = flags[1];
  __shared__ float keyT[DK][MEM];
  int t = threadIdx.x;
  for (int i=t;i<MEM*DK;i+=256){ int m=i&63, k=i>>6; keyT[k][m] = ldF(keym, (long)m*DK+k, f32m); }
  __syncthreads();
  long row = (long)blockIdx.x*256 + t;
  int qid = ldI(qd, row, i64m);
  long qb = (long)qid*DK;
  f32x4 A[16];
  #pragma unroll
  for (int g=0;g<16;g++) A[g] = (f32x4){0.f,0.f,0.f,0.f};
  for (int kk=0;kk<DK;kk+=8){
    float qv[8];
    if (f32m){
      const float* qp = (const float*)qW + qb + kk;
      f32x4 a=*(const f32x4*)qp, b=*(const f32x4*)(qp+4);
      qv[0]=a[0];qv[1]=a[1];qv[2]=a[2];qv[3]=a[3];qv[4]=b[0];qv[5]=b[1];qv[6]=b[2];qv[7]=b[3];
    } else {
      u16x8 u = *(const u16x8*)((const unsigned short*)qW + qb + kk);
      #pragma unroll
      for (int j=0;j<8;j++) qv[j]=bf2f(u[j]);
    }
    #pragma unroll
    for (int j=0;j<8;j++){
      float q = qv[j];
      #pragma unroll
      for (int g=0;g<16;g++){
        f32x4 kv = *(const f32x4*)&keyT[kk+j][g*4];
        f32x4 a = A[g];
        a[0]=fmaf(q,kv[0],a[0]); a[1]=fmaf(q,kv[1],a[1]);
        a[2]=fmaf(q,kv[2],a[2]); a[3]=fmaf(q,kv[3],a[3]);
        A[g]=a;
      }
    }
  }
  float mx = -1e30f;
  #pragma unroll
  for (int g=0;g<16;g++){
    f32x4 a = A[g];
    mx = fmaxf(mx, fmaxf(fmaxf(a[0],a[1]), fmaxf(a[2],a[3])));
  }
  float sum = 0.f;
  #pragma unroll
  for (int g=0;g<16;g++){
    f32x4 a = A[g];
    a[0]=__expf(a[0]-mx); a[1]=__expf(a[1]-mx); a[2]=__expf(a[2]-mx); a[3]=__expf(a[3]-mx);
    sum += (a[0]+a[1])+(a[2]+a[3]);
    A[g]=a;
  }
  float inv = 1.f/sum;
  float* outp = cw + row*MEM;
  #pragma unroll
  for (int g=0;g<16;g++){
    f32x4 a = A[g];
    f32x4 v = { a[0]*inv, a[1]*inv, a[2]*inv, a[3]*inv };
    *(f32x4*)(outp + g*4) = v;
  }
}

// ---------------- K2 (per-chunk): [erase|add] -> interleaved (er[d],ad[d]) u16 pairs ----------------
__global__ __launch_bounds__(256, 2) void k_ea(const int* __restrict__ qad, long row0,
    const void* __restrict__ qaW, const void* __restrict__ eW, const void* __restrict__ ebias,
    const void* __restrict__ aW, const void* __restrict__ abias,
    unsigned short* __restrict__ ea, const int* __restrict__ flags){
  const int f32m = flags[0], i64m = flags[1];
  __shared__ unsigned short As[128][40];
  __shared__ unsigned short Bs[128][40];
  __shared__ int rid[128];
  int t = threadIdx.x;
  int bm = blockIdx.x, bn = blockIdx.y;
  if (t<128) rid[t] = ldI(qad, row0 + (long)bm*128+t, i64m);
  int lane = t & 63, wid = t >> 6;
  int wr = wid >> 1, wc = wid & 1;
  f32x4 acc[4][4] = {};
  for (int k0=0;k0<DV;k0+=32){
    __syncthreads();
    #pragma unroll
    for (int j=0;j<2;j++){
      int c = t*2+j, r = c>>2, ko = (c&3)*8;
      st8(&As[r][ko], qaW, (long)rid[r]*DV + k0 + ko, f32m);
      int gn = bn*128 + r;
      if (gn < DV) st8(&Bs[r][ko], eW, (long)gn*DV + k0 + ko, f32m);
      else         st8(&Bs[r][ko], aW, (long)(gn-DV)*DV + k0 + ko, f32m);
    }
    __syncthreads();
    bf16x8 af[4], bfr[4];
    #pragma unroll
    for (int i=0;i<4;i++){
      af[i]  = __builtin_bit_cast(bf16x8, *(const u16x8*)&As[wr*64+i*16+(lane&15)][(lane>>4)*8]);
      bfr[i] = __builtin_bit_cast(bf16x8, *(const u16x8*)&Bs[wc*64+i*16+(lane&15)][(lane>>4)*8]);
    }
    #pragma unroll
    for (int i=0;i<4;i++)
      #pragma unroll
      for (int n=0;n<4;n++)
        acc[i][n] = __builtin_amdgcn_mfma_f32_16x16x32_bf16(af[i], bfr[n], acc[i][n],0,0,0);
  }
  #pragma unroll
  for (int i=0;i<4;i++)
    #pragma unroll
    for (int n=0;n<4;n++){
      int col = bn*128 + wc*64 + n*16 + (lane&15);
      float bias = (col<DV) ? ldF(ebias,col,f32m) : ldF(abias,col-DV,f32m);
      int dcol = (col<DV) ? 2*col : 2*(col-DV)+1;   // interleaved pair layout
      #pragma unroll
      for (int rix=0;rix<4;rix++){
        long rowg = (long)bm*128 + wr*64 + i*16 + (lane>>4)*4 + rix;
        float v = acc[i][n][rix] + bias;
        float o = (col<DV) ? sigf(v) : tanh_fast(v);
        ea[rowg*(2*DV) + dcol] = f2bfu(o);
      }
    }
}

// ---------------- K3 (per-chunk): scan — LDS-staged, 2 d-cols/thread, pk_fma + DPP ----------------
// block = one batch, 1024 threads: q = t&7 owns m in [8q,8q+8); dp = t>>3 owns d = {2dp, 2dp+1}
// per KS=16 steps: stage w (4KB) + ea (16KB) global->reg->LDS, double-buffered, 1 barrier
#define SCAN_STEP2(srel) { \
  wpair_t W0, W1; \
  W0.v4 = *(const f32x4*)(wb + (srel)*MEM); \
  W1.v4 = *(const f32x4*)(wb + (srel)*MEM + 4); \
  u32x2 uu = *(const u32x2*)(eb + (srel)*256); \
  float er0 = bf2f((unsigned short)(uu[0] & 0xFFFFu)); \
  float ad0 = bf2f((unsigned short)(uu[0] >> 16)); \
  float er1 = bf2f((unsigned short)(uu[1] & 0xFFFFu)); \
  float ad1 = bf2f((unsigned short)(uu[1] >> 16)); \
  f32x2 ner2a = {-er0, -er0}, ad2a = {ad0, ad0}; \
  f32x2 ner2b = {-er1, -er1}, ad2b = {ad1, ad1}; \
  f32x2 ra = {0.f, 0.f}, rb2 = {0.f, 0.f}; \
  _Pragma("unroll") \
  for (int jj=0; jj<4; jj++){ \
    f32x2 w2 = (jj<2) ? W0.v2[jj] : W1.v2[jj-2]; \
    pk_fma_acc(ra, w2, MA[jj]); \
    f32x2 tta = pk_fma(MA[jj], ner2a, ad2a); \
    pk_fma_acc(MA[jj], w2, tta); \
    pk_fma_acc(rb2, w2, MB[jj]); \
    f32x2 ttb = pk_fma(MB[jj], ner2b, ad2b); \
    pk_fma_acc(MB[jj], w2, ttb); \
  } \
  float r0 = ra[0] + ra[1]; \
  float r1 = rb2[0] + rb2[1]; \
  DPP_ADD(r0, 0x111); DPP_ADD(r0, 0x112); DPP_ADD(r0, 0x114); \
  DPP_ADD(r1, 0x111); DPP_ADD(r1, 0x112); DPP_ADD(r1, 0x114); \
  if (q == 7){ \
    unsigned pk = ((unsigned)f2bfu(r1) << 16) | (unsigned)f2bfu(r0); \
    rdu[(srel)*128] = pk; \
  } \
}

__global__ __launch_bounds__(1024, 4) void k_scan(const float* __restrict__ cw,
    const unsigned short* __restrict__ ea, const void* __restrict__ initm,
    unsigned short* __restrict__ rdout, const int* __restrict__ flags){
  const int f32m = flags[0];
  __shared__ float        w_lds[2][KS][MEM];     // 8 KB
  __shared__ unsigned int ea_lds[2][KS][DV];     // 32 KB (256 u32 per step row)
  int b = blockIdx.x;
  int t = threadIdx.x;
  int q = t & 7;
  int dp = t >> 3;              // 0..127
  int d0 = 2*dp;
  int m0 = q * 8;

  // state: MA = d0 column (4 m-pairs), MB = d1 column
  f32x2 MA[4], MB[4];
  #pragma unroll
  for (int g=0; g<4; g++){
    f32x2 va, vb;
    va[0] = ldF(initm, (long)(m0+2*g+0)*DV + d0, f32m);
    va[1] = ldF(initm, (long)(m0+2*g+1)*DV + d0, f32m);
    vb[0] = ldF(initm, (long)(m0+2*g+0)*DV + d0+1, f32m);
    vb[1] = ldF(initm, (long)(m0+2*g+1)*DV + d0+1, f32m);
    MA[g] = va; MB[g] = vb;
  }

  const float* cwb = cw + (long)b*SEQ*MEM;
  const unsigned int* epb = (const unsigned int*)(ea + (long)b*SEQ*(2*DV));  // 256 u32/step
  unsigned int* rdu = (unsigned int*)(rdout + (long)b*SEQ*DV) + dp;

  // prologue: stage 0 (steps 0..15) into buffer 0
  {
    float wreg = cwb[t];
    u32x4 ereg = *(const u32x4*)(epb + t*4);
    ((float*)w_lds[0])[t] = wreg;
    *(u32x4*)((unsigned int*)ea_lds[0] + t*4) = ereg;
  }
  __syncthreads();

  int cur = 0;
  // main: 31 stages x 16 steps = 496 steps
  for (int st = 0; st < 31; st++){
    // issue next-stage global loads early (latency hides under 16 steps of compute)
    float wnext = cwb[(st+1)*KS*MEM + t];
    u32x4 enext = *(const u32x4*)(epb + (st+1)*KS*DV + t*4);

    const float* wb        = (const float*)w_lds[cur] + m0;
    const unsigned int* eb = (const unsigned int*)ea_lds[cur] + d0;
    #pragma unroll
    for (int srel=0; srel<KS; srel++){
      SCAN_STEP2(srel);
    }
    // write next stage into the other buffer, then barrier
    ((float*)w_lds[cur^1])[t] = wnext;
    *(u32x4*)((unsigned int*)ea_lds[cur^1] + t*4) = enext;
    rdu += KS*128;
    __syncthreads();
    cur ^= 1;
  }
  // tail: steps 496..499 from buffer cur
  {
    const float* wb        = (const float*)w_lds[cur] + m0;
    const unsigned int* eb = (const unsigned int*)ea_lds[cur] + d0;
    #pragma unroll
    for (int srel=0; srel<4; srel++){
      SCAN_STEP2(srel);
    }
  }
}

// ---------------- K4 (per-chunk): h = tanh([reads|q_e] @ rW^T + rb); logit; BCE ----------------
__global__ __launch_bounds__(256, 2) void k_pred(const int* __restrict__ qd, long row0,
    const void* __restrict__ qW, const unsigned short* __restrict__ rds,
    const void* __restrict__ rW, const void* __restrict__ rb,
    const void* __restrict__ pW, const void* __restrict__ pb,
    const void* __restrict__ target,
    void* __restrict__ out, float* __restrict__ accum,
    const int* __restrict__ flags){
  const int f32m = flags[0], i64m = flags[1];
  __shared__ unsigned short As[128][40];
  __shared__ unsigned short Bs[128][40];
  __shared__ unsigned short hs[128][136];
  __shared__ int rid[128];
  int t = threadIdx.x;
  int bm = blockIdx.x;
  if (t<128) rid[t] = ldI(qd, row0 + (long)bm*128+t, i64m);
  int lane=t&63, wid=t>>6, wr=wid>>1, wc=wid&1;
  f32x4 acc[4][4] = {};
  for (int k0=0;k0<(DV+DK);k0+=32){
    __syncthreads();
    #pragma unroll
    for (int j=0;j<2;j++){
      int c=t*2+j, r=c>>2, ko=(c&3)*8;
      if (k0 < DV) st8(&As[r][ko], rds, ((long)bm*128+r)*DV + k0+ko, 0);
      else         st8(&As[r][ko], qW, (long)rid[r]*DK + (k0-DV)+ko, f32m);
      st8(&Bs[r][ko], rW, (long)r*(DV+DK) + k0+ko, f32m);
    }
    __syncthreads();
    bf16x8 af[4], bfr[4];
    #pragma unroll
    for (int i=0;i<4;i++){
      af[i]  = __builtin_bit_cast(bf16x8, *(const u16x8*)&As[wr*64+i*16+(lane&15)][(lane>>4)*8]);
      bfr[i] = __builtin_bit_cast(bf16x8, *(const u16x8*)&Bs[wc*64+i*16+(lane&15)][(lane>>4)*8]);
    }
    #pragma unroll
    for (int i=0;i<4;i++)
      #pragma unroll
      for (int n=0;n<4;n++)
        acc[i][n] = __builtin_amdgcn_mfma_f32_16x16x32_bf16(af[i], bfr[n], acc[i][n],0,0,0);
  }
  #pragma unroll
  for (int i=0;i<4;i++)
    #pragma unroll
    for (int n=0;n<4;n++){
      int col = wc*64 + n*16 + (lane&15);
      float bias = ldF(rb, col, f32m);
      #pragma unroll
      for (int rix=0;rix<4;rix++){
        int rowl = wr*64 + i*16 + (lane>>4)*4 + rix;
        hs[rowl][col] = f2bfu(tanh_fast(acc[i][n][rix] + bias));
      }
    }
  __syncthreads();
  float bces = 0.f, cnts = 0.f;
  if (t < 128){
    float lg = ldF(pb, 0, f32m);
    #pragma unroll
    for (int cc=0;cc<FC;cc++) lg = fmaf(bf2f(hs[t][cc]), ldF(pW, cc, f32m), lg);
    long rowg = row0 + (long)bm*128 + t;
    float tg = ldF(target, rowg, f32m);
    bool mask = tg >= 0.f;
    float e = __expf(-fabsf(lg));
    float bce = fmaxf(lg, 0.f) - lg*tg + __logf(1.f + e);
    bces = mask ? bce : 0.f;
    cnts = mask ? 1.f : 0.f;
    stOut(out, 1 + rowg, mask ? sigf(lg) : 0.f, f32m);
    stOut(out, 1 + BS + rowg, mask ? tg : 0.f, f32m);
  }
  #pragma unroll
  for (int off=32; off>0; off>>=1){ bces += __shfl_down(bces, off); cnts += __shfl_down(cnts, off); }
  if ((t & 63) == 0 && t < 128){
    atomicAdd(&accum[0], bces);
    atomicAdd(&accum[1], cnts);
  }
}

__global__ void k_loss(const float* __restrict__ accum, void* __restrict__ out,
                       const int* __restrict__ flags){
  if (threadIdx.x == 0){
    float denom = fmaxf(accum[1], 1.f);
    stOut(out, 0, accum[0]/denom, flags[0]);
  }
}

extern "C" void kernel_launch(void* const* d_in, const int* in_sizes, int n_in,
                              void* d_out, int out_size, void* d_ws, size_t ws_size,
                              hipStream_t stream) {
  const int* q_data  = (const int*)d_in[0];
  const int* qa_data = (const int*)d_in[1];
  const void* target = d_in[2];
  const void* qW   = d_in[3];
  const void* qaW  = d_in[4];
  const void* keym = d_in[5];
  const void* initm= d_in[6];
  const void* eW   = d_in[7];
  const void* eb   = d_in[8];
  const void* aW   = d_in[9];
  const void* ab   = d_in[10];
  const void* rW   = d_in[11];
  const void* rb   = d_in[12];
  const void* pW   = d_in[13];
  const void* pb   = d_in[14];

  char* ws = (char*)d_ws;
  const size_t CW_OFF = 256;
  const size_t CW_BYTES = (size_t)BS*MEM*4;              // 65,536,000
  const size_t EA_OFF = CW_OFF + CW_BYTES;
  float* accum = (float*)ws;
  int* flags = (int*)(ws + 64);
  float* cw = (float*)(ws + CW_OFF);

  const long per_batch = (long)SEQ*(2*DV)*2 + (long)SEQ*DV*2;  // 768000 B per batch
  long rem = (long)ws_size - (long)EA_OFF;
  int bchunk = 512;
  while (bchunk > 32 && per_batch*bchunk > rem) bchunk >>= 1;  // 512,256,128,64,32

  const size_t EA_BYTES = (size_t)bchunk*SEQ*(2*DV)*2;
  unsigned short* ea = (unsigned short*)(ws + EA_OFF);
  unsigned short* rd = (unsigned short*)(ws + EA_OFF + EA_BYTES);

  k_detect<<<1, 64, 0, stream>>>((const unsigned short*)keym, qa_data, flags, accum);
  k_cw  <<<BS/256, 256, 0, stream>>>(q_data, qW, keym, cw, flags);

  int nchunk = BATCH / bchunk;
  for (int c = 0; c < nchunk; c++){
    long b0 = (long)c * bchunk;
    int rows = bchunk * SEQ;
    k_ea  <<<dim3(rows/128, 4), 256, 0, stream>>>(qa_data, b0*SEQ, qaW, eW, eb, aW, ab, ea, flags);
    k_scan<<<bchunk, 1024, 0, stream>>>(cw + b0*SEQ*MEM, ea, initm, rd, flags);
    k_pred<<<rows/128, 256, 0, stream>>>(q_data, b0*SEQ, qW, rd, rW, rb, pW, pb,
                                         target, d_out, accum, flags);
  }
  k_loss<<<1, 64, 0, stream>>>(accum, d_out, flags);
}

// Round 12
// 1058.194 us; speedup vs baseline: 1.3337x; 1.0710x over previous
//
#include <hip/hip_runtime.h>
#include <hip/hip_bf16.h>

#define BATCH 512
#define SEQ   500
#define BS    (BATCH*SEQ)     // 256000
#define MEM   64
#define DK    128
#define DV    256
#define FC    128
#define KS    16              // scan steps per LDS stage

typedef float f32x4 __attribute__((ext_vector_type(4)));
typedef unsigned int u32x4 __attribute__((ext_vector_type(4)));
typedef unsigned int u32x2 __attribute__((ext_vector_type(2)));
typedef unsigned short u16x8 __attribute__((ext_vector_type(8)));
typedef __bf16 bf16x8 __attribute__((ext_vector_type(8)));

__device__ __forceinline__ float bf2f(unsigned short u){ return __uint_as_float(((unsigned)u)<<16); }
__device__ __forceinline__ unsigned short f2bfu(float x){
  unsigned u = __float_as_uint(x);
  return (unsigned short)((u + 0x7FFFu + ((u>>16)&1u)) >> 16);  // RNE
}
__device__ __forceinline__ float sigf(float x){ return 1.f/(1.f+__expf(-x)); }
__device__ __forceinline__ float tanh_fast(float x){ return 2.f/(1.f+__expf(-2.f*x)) - 1.f; }

// DPP row-shift add: after shr:1, shr:2, shr:4 the 8-lane-group sum lands in lane q==7.
#define DPP_ADD(r, ctrl) { \
  int _s = __builtin_amdgcn_update_dpp(0, __builtin_bit_cast(int, r), ctrl, 0xF, 0xF, true); \
  r += __builtin_bit_cast(float, _s); \
}

__device__ __forceinline__ float ldF(const void* p, long i, int f32m){
  return f32m ? ((const float*)p)[i] : bf2f(((const unsigned short*)p)[i]);
}
__device__ __forceinline__ int ldI(const int* p, long i, int i64m){
  return i64m ? p[2*i] : p[i];   // little-endian low word of int64
}
__device__ __forceinline__ void st8(unsigned short* dst, const void* src, long i, int f32m){
  if (f32m){
    const float* q = (const float*)src + i;
    f32x4 a = *(const f32x4*)q;
    f32x4 b = *(const f32x4*)(q+4);
    u16x8 o;
    o[0]=f2bfu(a[0]); o[1]=f2bfu(a[1]); o[2]=f2bfu(a[2]); o[3]=f2bfu(a[3]);
    o[4]=f2bfu(b[0]); o[5]=f2bfu(b[1]); o[6]=f2bfu(b[2]); o[7]=f2bfu(b[3]);
    *(u16x8*)dst = o;
  } else {
    *(u16x8*)dst = *(const u16x8*)((const unsigned short*)src + i);
  }
}
__device__ __forceinline__ void stOut(void* p, long i, float x, int f32m){
  if (f32m) ((float*)p)[i] = x;
  else ((unsigned short*)p)[i] = f2bfu(x);
}

// ---------------- K0: dtype detection + accum zero ----------------
__global__ void k_detect(const unsigned short* __restrict__ km, const int* __restrict__ qa,
                         int* __restrict__ flags, float* __restrict__ accum){
  int t = threadIdx.x;            // 64 threads, one wave
  if (t < 2) accum[t] = 0.f;
  unsigned short u = km[2*t];     // even u16 halves of key_memory
  int e = (u >> 7) & 0xFF;
  bool sane = (e==0) || (e>=100 && e<=140);
  unsigned long long sm = __ballot(sane);
  unsigned long long zm = __ballot(qa[2*t+1] == 0);
  if (t == 0){
    flags[0] = (__popcll(sm) < 48) ? 1 : 0;               // 1 = f32 float buffers
    flags[1] = (zm == 0xFFFFFFFFFFFFFFFFull) ? 1 : 0;     // 1 = int64 index buffers
  }
}

// ---------------- K1: cw = softmax(q_e @ key^T) ----------------
__global__ __launch_bounds__(256, 2) void k_cw(const int* __restrict__ qd,
    const void* __restrict__ qW, const void* __restrict__ keym,
    float* __restrict__ cw, const int* __restrict__ flags){
  const int f32m = flags[0], i64m = flags[1];
  __shared__ float keyT[DK][MEM];
  int t = threadIdx.x;
  for (int i=t;i<MEM*DK;i+=256){ int m=i&63, k=i>>6; keyT[k][m] = ldF(keym, (long)m*DK+k, f32m); }
  __syncthreads();
  long row = (long)blockIdx.x*256 + t;
  int qid = ldI(qd, row, i64m);
  long qb = (long)qid*DK;
  f32x4 A[16];
  #pragma unroll
  for (int g=0;g<16;g++) A[g] = (f32x4){0.f,0.f,0.f,0.f};
  for (int kk=0;kk<DK;kk+=8){
    float qv[8];
    if (f32m){
      const float* qp = (const float*)qW + qb + kk;
      f32x4 a=*(const f32x4*)qp, b=*(const f32x4*)(qp+4);
      qv[0]=a[0];qv[1]=a[1];qv[2]=a[2];qv[3]=a[3];qv[4]=b[0];qv[5]=b[1];qv[6]=b[2];qv[7]=b[3];
    } else {
      u16x8 u = *(const u16x8*)((const unsigned short*)qW + qb + kk);
      #pragma unroll
      for (int j=0;j<8;j++) qv[j]=bf2f(u[j]);
    }
    #pragma unroll
    for (int j=0;j<8;j++){
      float q = qv[j];
      #pragma unroll
      for (int g=0;g<16;g++){
        f32x4 kv = *(const f32x4*)&keyT[kk+j][g*4];
        f32x4 a = A[g];
        a[0]=fmaf(q,kv[0],a[0]); a[1]=fmaf(q,kv[1],a[1]);
        a[2]=fmaf(q,kv[2],a[2]); a[3]=fmaf(q,kv[3],a[3]);
        A[g]=a;
      }
    }
  }
  float mx = -1e30f;
  #pragma unroll
  for (int g=0;g<16;g++){
    f32x4 a = A[g];
    mx = fmaxf(mx, fmaxf(fmaxf(a[0],a[1]), fmaxf(a[2],a[3])));
  }
  float sum = 0.f;
  #pragma unroll
  for (int g=0;g<16;g++){
    f32x4 a = A[g];
    a[0]=__expf(a[0]-mx); a[1]=__expf(a[1]-mx); a[2]=__expf(a[2]-mx); a[3]=__expf(a[3]-mx);
    sum += (a[0]+a[1])+(a[2]+a[3]);
    A[g]=a;
  }
  float inv = 1.f/sum;
  float* outp = cw + row*MEM;
  #pragma unroll
  for (int g=0;g<16;g++){
    f32x4 a = A[g];
    f32x4 v = { a[0]*inv, a[1]*inv, a[2]*inv, a[3]*inv };
    *(f32x4*)(outp + g*4) = v;
  }
}

// ---------------- K2 (per-chunk): [erase|add] -> interleaved (er[d],ad[d]) u16 pairs ----------------
__global__ __launch_bounds__(256, 2) void k_ea(const int* __restrict__ qad, long row0,
    const void* __restrict__ qaW, const void* __restrict__ eW, const void* __restrict__ ebias,
    const void* __restrict__ aW, const void* __restrict__ abias,
    unsigned short* __restrict__ ea, const int* __restrict__ flags){
  const int f32m = flags[0], i64m = flags[1];
  __shared__ unsigned short As[128][40];
  __shared__ unsigned short Bs[128][40];
  __shared__ int rid[128];
  int t = threadIdx.x;
  int bm = blockIdx.x, bn = blockIdx.y;
  if (t<128) rid[t] = ldI(qad, row0 + (long)bm*128+t, i64m);
  int lane = t & 63, wid = t >> 6;
  int wr = wid >> 1, wc = wid & 1;
  f32x4 acc[4][4] = {};
  for (int k0=0;k0<DV;k0+=32){
    __syncthreads();
    #pragma unroll
    for (int j=0;j<2;j++){
      int c = t*2+j, r = c>>2, ko = (c&3)*8;
      st8(&As[r][ko], qaW, (long)rid[r]*DV + k0 + ko, f32m);
      int gn = bn*128 + r;
      if (gn < DV) st8(&Bs[r][ko], eW, (long)gn*DV + k0 + ko, f32m);
      else         st8(&Bs[r][ko], aW, (long)(gn-DV)*DV + k0 + ko, f32m);
    }
    __syncthreads();
    bf16x8 af[4], bfr[4];
    #pragma unroll
    for (int i=0;i<4;i++){
      af[i]  = __builtin_bit_cast(bf16x8, *(const u16x8*)&As[wr*64+i*16+(lane&15)][(lane>>4)*8]);
      bfr[i] = __builtin_bit_cast(bf16x8, *(const u16x8*)&Bs[wc*64+i*16+(lane&15)][(lane>>4)*8]);
    }
    #pragma unroll
    for (int i=0;i<4;i++)
      #pragma unroll
      for (int n=0;n<4;n++)
        acc[i][n] = __builtin_amdgcn_mfma_f32_16x16x32_bf16(af[i], bfr[n], acc[i][n],0,0,0);
  }
  #pragma unroll
  for (int i=0;i<4;i++)
    #pragma unroll
    for (int n=0;n<4;n++){
      int col = bn*128 + wc*64 + n*16 + (lane&15);
      float bias = (col<DV) ? ldF(ebias,col,f32m) : ldF(abias,col-DV,f32m);
      int dcol = (col<DV) ? 2*col : 2*(col-DV)+1;   // interleaved pair layout
      #pragma unroll
      for (int rix=0;rix<4;rix++){
        long rowg = (long)bm*128 + wr*64 + i*16 + (lane>>4)*4 + rix;
        float v = acc[i][n][rix] + bias;
        float o = (col<DV) ? sigf(v) : tanh_fast(v);
        ea[rowg*(2*DV) + dcol] = f2bfu(o);
      }
    }
}

// ---------------- K3 (per-chunk): scan — LDS-staged, 2 d-cols/thread, scalar FMA + DPP ----------------
// block = one batch, 1024 threads: q = t&7 owns m in [8q,8q+8); dp = t>>3 owns d = {2dp, 2dp+1}
// per KS=16 steps: stage w (4KB) + ea (16KB) global->reg->LDS, double-buffered, 1 barrier
// update: ta = m*er - ad (fused, -ad as modifier); m = m + (-w)*ta  == m - w*(m*er - ad)
#define SCAN_STEP2(srel) { \
  f32x4 W0 = *(const f32x4*)(wb + (srel)*MEM); \
  f32x4 W1 = *(const f32x4*)(wb + (srel)*MEM + 4); \
  u32x2 uu = *(const u32x2*)(eb + (srel)*256); \
  float er0 = __uint_as_float(uu[0] << 16); \
  float ad0 = __uint_as_float(uu[0] & 0xFFFF0000u); \
  float er1 = __uint_as_float(uu[1] << 16); \
  float ad1 = __uint_as_float(uu[1] & 0xFFFF0000u); \
  float ra0=0.f, ra1=0.f, rb0=0.f, rb1=0.f; \
  _Pragma("unroll") \
  for (int j=0; j<8; j++){ \
    float w = (j<4) ? W0[j] : W1[j-4]; \
    if (j & 1) ra1 = fmaf(w, MA[j], ra1); else ra0 = fmaf(w, MA[j], ra0); \
    float ta = fmaf(MA[j], er0, -ad0); \
    MA[j] = fmaf(-w, ta, MA[j]); \
    if (j & 1) rb1 = fmaf(w, MB[j], rb1); else rb0 = fmaf(w, MB[j], rb0); \
    float tb = fmaf(MB[j], er1, -ad1); \
    MB[j] = fmaf(-w, tb, MB[j]); \
  } \
  float r0 = ra0 + ra1; \
  float r1 = rb0 + rb1; \
  DPP_ADD(r0, 0x111); DPP_ADD(r0, 0x112); DPP_ADD(r0, 0x114); \
  DPP_ADD(r1, 0x111); DPP_ADD(r1, 0x112); DPP_ADD(r1, 0x114); \
  if (q == 7){ \
    unsigned pk; \
    asm("v_cvt_pk_bf16_f32 %0, %1, %2" : "=v"(pk) : "v"(r0), "v"(r1)); \
    rdu[(srel)*128] = pk; \
  } \
}

__global__ __launch_bounds__(1024, 4) void k_scan(const float* __restrict__ cw,
    const unsigned short* __restrict__ ea, const void* __restrict__ initm,
    unsigned short* __restrict__ rdout, const int* __restrict__ flags){
  const int f32m = flags[0];
  __shared__ float        w_lds[2][KS][MEM];     // 8 KB
  __shared__ unsigned int ea_lds[2][KS][DV];     // 32 KB (256 u32 per step row)
  int b = blockIdx.x;
  int t = threadIdx.x;
  int q = t & 7;
  int dp = t >> 3;              // 0..127
  int d0 = 2*dp;
  int m0 = q * 8;

  // state: MA = d0 column (8 m rows), MB = d1 column
  float MA[8], MB[8];
  #pragma unroll
  for (int g=0; g<8; g++){
    MA[g] = ldF(initm, (long)(m0+g)*DV + d0,   f32m);
    MB[g] = ldF(initm, (long)(m0+g)*DV + d0+1, f32m);
  }

  const float* cwb = cw + (long)b*SEQ*MEM;
  const unsigned int* epb = (const unsigned int*)(ea + (long)b*SEQ*(2*DV));  // 256 u32/step
  unsigned int* rdu = (unsigned int*)(rdout + (long)b*SEQ*DV) + dp;

  // prologue: stage 0 (steps 0..15) into buffer 0
  {
    float wreg = cwb[t];
    u32x4 ereg = *(const u32x4*)(epb + t*4);
    ((float*)w_lds[0])[t] = wreg;
    *(u32x4*)((unsigned int*)ea_lds[0] + t*4) = ereg;
  }
  __syncthreads();

  int cur = 0;
  // main: 31 stages x 16 steps = 496 steps
  for (int st = 0; st < 31; st++){
    // issue next-stage global loads early (latency hides under 16 steps of compute)
    float wnext = cwb[(st+1)*KS*MEM + t];
    u32x4 enext = *(const u32x4*)(epb + (st+1)*KS*DV + t*4);

    const float* wb        = (const float*)w_lds[cur] + m0;
    const unsigned int* eb = (const unsigned int*)ea_lds[cur] + d0;
    #pragma unroll
    for (int srel=0; srel<KS; srel++){
      SCAN_STEP2(srel);
    }
    // write next stage into the other buffer, then barrier
    ((float*)w_lds[cur^1])[t] = wnext;
    *(u32x4*)((unsigned int*)ea_lds[cur^1] + t*4) = enext;
    rdu += KS*128;
    __syncthreads();
    cur ^= 1;
  }
  // tail: steps 496..499 from buffer cur
  {
    const float* wb        = (const float*)w_lds[cur] + m0;
    const unsigned int* eb = (const unsigned int*)ea_lds[cur] + d0;
    #pragma unroll
    for (int srel=0; srel<4; srel++){
      SCAN_STEP2(srel);
    }
  }
}

// ---------------- K4 (per-chunk): h = tanh([reads|q_e] @ rW^T + rb); logit; BCE ----------------
__global__ __launch_bounds__(256, 2) void k_pred(const int* __restrict__ qd, long row0,
    const void* __restrict__ qW, const unsigned short* __restrict__ rds,
    const void* __restrict__ rW, const void* __restrict__ rb,
    const void* __restrict__ pW, const void* __restrict__ pb,
    const void* __restrict__ target,
    void* __restrict__ out, float* __restrict__ accum,
    const int* __restrict__ flags){
  const int f32m = flags[0], i64m = flags[1];
  __shared__ unsigned short As[128][40];
  __shared__ unsigned short Bs[128][40];
  __shared__ unsigned short hs[128][136];
  __shared__ int rid[128];
  int t = threadIdx.x;
  int bm = blockIdx.x;
  if (t<128) rid[t] = ldI(qd, row0 + (long)bm*128+t, i64m);
  int lane=t&63, wid=t>>6, wr=wid>>1, wc=wid&1;
  f32x4 acc[4][4] = {};
  for (int k0=0;k0<(DV+DK);k0+=32){
    __syncthreads();
    #pragma unroll
    for (int j=0;j<2;j++){
      int c=t*2+j, r=c>>2, ko=(c&3)*8;
      if (k0 < DV) st8(&As[r][ko], rds, ((long)bm*128+r)*DV + k0+ko, 0);
      else         st8(&As[r][ko], qW, (long)rid[r]*DK + (k0-DV)+ko, f32m);
      st8(&Bs[r][ko], rW, (long)r*(DV+DK) + k0+ko, f32m);
    }
    __syncthreads();
    bf16x8 af[4], bfr[4];
    #pragma unroll
    for (int i=0;i<4;i++){
      af[i]  = __builtin_bit_cast(bf16x8, *(const u16x8*)&As[wr*64+i*16+(lane&15)][(lane>>4)*8]);
      bfr[i] = __builtin_bit_cast(bf16x8, *(const u16x8*)&Bs[wc*64+i*16+(lane&15)][(lane>>4)*8]);
    }
    #pragma unroll
    for (int i=0;i<4;i++)
      #pragma unroll
      for (int n=0;n<4;n++)
        acc[i][n] = __builtin_amdgcn_mfma_f32_16x16x32_bf16(af[i], bfr[n], acc[i][n],0,0,0);
  }
  #pragma unroll
  for (int i=0;i<4;i++)
    #pragma unroll
    for (int n=0;n<4;n++){
      int col = wc*64 + n*16 + (lane&15);
      float bias = ldF(rb, col, f32m);
      #pragma unroll
      for (int rix=0;rix<4;rix++){
        int rowl = wr*64 + i*16 + (lane>>4)*4 + rix;
        hs[rowl][col] = f2bfu(tanh_fast(acc[i][n][rix] + bias));
      }
    }
  __syncthreads();
  float bces = 0.f, cnts = 0.f;
  if (t < 128){
    float lg = ldF(pb, 0, f32m);
    #pragma unroll
    for (int cc=0;cc<FC;cc++) lg = fmaf(bf2f(hs[t][cc]), ldF(pW, cc, f32m), lg);
    long rowg = row0 + (long)bm*128 + t;
    float tg = ldF(target, rowg, f32m);
    bool mask = tg >= 0.f;
    float e = __expf(-fabsf(lg));
    float bce = fmaxf(lg, 0.f) - lg*tg + __logf(1.f + e);
    bces = mask ? bce : 0.f;
    cnts = mask ? 1.f : 0.f;
    stOut(out, 1 + rowg, mask ? sigf(lg) : 0.f, f32m);
    stOut(out, 1 + BS + rowg, mask ? tg : 0.f, f32m);
  }
  #pragma unroll
  for (int off=32; off>0; off>>=1){ bces += __shfl_down(bces, off); cnts += __shfl_down(cnts, off); }
  if ((t & 63) == 0 && t < 128){
    atomicAdd(&accum[0], bces);
    atomicAdd(&accum[1], cnts);
  }
}

__global__ void k_loss(const float* __restrict__ accum, void* __restrict__ out,
                       const int* __restrict__ flags){
  if (threadIdx.x == 0){
    float denom = fmaxf(accum[1], 1.f);
    stOut(out, 0, accum[0]/denom, flags[0]);
  }
}

extern "C" void kernel_launch(void* const* d_in, const int* in_sizes, int n_in,
                              void* d_out, int out_size, void* d_ws, size_t ws_size,
                              hipStream_t stream) {
  const int* q_data  = (const int*)d_in[0];
  const int* qa_data = (const int*)d_in[1];
  const void* target = d_in[2];
  const void* qW   = d_in[3];
  const void* qaW  = d_in[4];
  const void* keym = d_in[5];
  const void* initm= d_in[6];
  const void* eW   = d_in[7];
  const void* eb   = d_in[8];
  const void* aW   = d_in[9];
  const void* ab   = d_in[10];
  const void* rW   = d_in[11];
  const void* rb   = d_in[12];
  const void* pW   = d_in[13];
  const void* pb   = d_in[14];

  char* ws = (char*)d_ws;
  const size_t CW_OFF = 256;
  const size_t CW_BYTES = (size_t)BS*MEM*4;              // 65,536,000
  const size_t EA_OFF = CW_OFF + CW_BYTES;
  float* accum = (float*)ws;
  int* flags = (int*)(ws + 64);
  float* cw = (float*)(ws + CW_OFF);

  const long per_batch = (long)SEQ*(2*DV)*2 + (long)SEQ*DV*2;  // 768000 B per batch
  long rem = (long)ws_size - (long)EA_OFF;
  int bchunk = 512;
  while (bchunk > 32 && per_batch*bchunk > rem) bchunk >>= 1;  // 512,256,128,64,32

  const size_t EA_BYTES = (size_t)bchunk*SEQ*(2*DV)*2;
  unsigned short* ea = (unsigned short*)(ws + EA_OFF);
  unsigned short* rd = (unsigned short*)(ws + EA_OFF + EA_BYTES);

  k_detect<<<1, 64, 0, stream>>>((const unsigned short*)keym, qa_data, flags, accum);
  k_cw  <<<BS/256, 256, 0, stream>>>(q_data, qW, keym, cw, flags);

  int nchunk = BATCH / bchunk;
  for (int c = 0; c < nchunk; c++){
    long b0 = (long)c * bchunk;
    int rows = bchunk * SEQ;
    k_ea  <<<dim3(rows/128, 4), 256, 0, stream>>>(qa_data, b0*SEQ, qaW, eW, eb, aW, ab, ea, flags);
    k_scan<<<bchunk, 1024, 0, stream>>>(cw + b0*SEQ*MEM, ea, initm, rd, flags);
    k_pred<<<rows/128, 256, 0, stream>>>(q_data, b0*SEQ, qW, rd, rW, rb, pW, pb,
                                         target, d_out, accum, flags);
  }
  k_loss<<<1, 64, 0, stream>>>(accum, d_out, flags);
}